// Round 3
// baseline (1381.712 us; speedup 1.0000x reference)
//
#include <hip/hip_runtime.h>
#include <hip/hip_bf16.h>

#define D_MODEL 1024
#define D_INNER 2048
#define D_STATE 16
#define D_CONV  4
#define DT_RANK 64
#define B_SZ    2
#define L_SEQ   1024
#define BL      (B_SZ * L_SEQ)          // 2048 rows
#define NPROJ   (DT_RANK + 2 * D_STATE) // 96

// C[M,N] = A[M,K] @ B[N,K]^T  (all fp32; B row-major as stored weight [N,K])
// EPI: 0 = none, 1 = softplus(acc + bias[n])
template <int EPI>
__global__ __launch_bounds__(256) void gemm_btn(
    const float* __restrict__ A, int lda,
    const float* __restrict__ Bw, int ldb,
    float* __restrict__ C, int ldc,
    int M, int N, int K,
    const float* __restrict__ bias)
{
    __shared__ float As[16][65];
    __shared__ float Bs[16][65];

    const int tid = threadIdx.x;
    const int bm = blockIdx.y * 64;
    const int bn = blockIdx.x * 64;

    const int tx = tid & 15;   // n-tile lane (x4)
    const int ty = tid >> 4;   // m-tile lane (x4)

    const int lrow = tid >> 2; // 0..63 : row within tile for staging
    const int lcg  = tid & 3;  // 0..3  : k-group (x4) for staging

    float acc[4][4];
#pragma unroll
    for (int i = 0; i < 4; ++i)
#pragma unroll
        for (int j = 0; j < 4; ++j) acc[i][j] = 0.f;

    for (int k0 = 0; k0 < K; k0 += 16) {
        // stage A tile (64 rows x 16 k), transposed into As[k][m]
        {
            const int ar = bm + lrow;
            float4 v = make_float4(0.f, 0.f, 0.f, 0.f);
            if (ar < M)
                v = *(const float4*)(A + (size_t)ar * lda + k0 + lcg * 4);
            As[lcg * 4 + 0][lrow] = v.x;
            As[lcg * 4 + 1][lrow] = v.y;
            As[lcg * 4 + 2][lrow] = v.z;
            As[lcg * 4 + 3][lrow] = v.w;
        }
        // stage B tile (64 n-rows x 16 k), transposed into Bs[k][n]
        {
            const int br = bn + lrow;
            float4 v = make_float4(0.f, 0.f, 0.f, 0.f);
            if (br < N)
                v = *(const float4*)(Bw + (size_t)br * ldb + k0 + lcg * 4);
            Bs[lcg * 4 + 0][lrow] = v.x;
            Bs[lcg * 4 + 1][lrow] = v.y;
            Bs[lcg * 4 + 2][lrow] = v.z;
            Bs[lcg * 4 + 3][lrow] = v.w;
        }
        __syncthreads();

#pragma unroll
        for (int kk = 0; kk < 16; ++kk) {
            float a[4], b[4];
#pragma unroll
            for (int i = 0; i < 4; ++i) a[i] = As[kk][ty * 4 + i];
#pragma unroll
            for (int j = 0; j < 4; ++j) b[j] = Bs[kk][tx * 4 + j];
#pragma unroll
            for (int i = 0; i < 4; ++i)
#pragma unroll
                for (int j = 0; j < 4; ++j) acc[i][j] += a[i] * b[j];
        }
        __syncthreads();
    }

#pragma unroll
    for (int i = 0; i < 4; ++i) {
        const int m = bm + ty * 4 + i;
        if (m >= M) continue;
#pragma unroll
        for (int j = 0; j < 4; ++j) {
            const int n = bn + tx * 4 + j;
            if (n >= N) continue;
            float v = acc[i][j];
            if (EPI == 1) {
                v += bias[n];
                v = (v > 20.f) ? v : log1pf(__expf(v));
            }
            C[(size_t)m * ldc + n] = v;
        }
    }
}

// depthwise causal conv1d + bias + SiLU. xz layout: [(b*L+t), 4096]; x_br = cols 0..2047
__global__ __launch_bounds__(256) void conv_silu(
    const float* __restrict__ xz,
    const float* __restrict__ conv_w,
    const float* __restrict__ conv_b,
    float* __restrict__ u)
{
    const int idx = blockIdx.x * blockDim.x + threadIdx.x; // (b*L+t)*2048 + d
    const int d  = idx & (D_INNER - 1);
    const int bt = idx >> 11;          // b*L + t
    const int t  = bt & (L_SEQ - 1);

    const float w0 = conv_w[d * 4 + 0];
    const float w1 = conv_w[d * 4 + 1];
    const float w2 = conv_w[d * 4 + 2];
    const float w3 = conv_w[d * 4 + 3];

    const float* col = xz + (size_t)bt * (2 * D_INNER) + d;
    float acc = conv_b[d];
    if (t >= 3) acc += col[-3 * 2 * D_INNER] * w0;
    if (t >= 2) acc += col[-2 * 2 * D_INNER] * w1;
    if (t >= 1) acc += col[-1 * 2 * D_INNER] * w2;
    acc += col[0] * w3;

    const float s = acc / (1.f + __expf(-acc)); // silu
    u[idx] = s;
}

// Sequential SSM scan: one thread per (b, d). Fused D skip + output gate silu(z).
// delta lives in xz cols 0..2047 (stride 4096); z in xz cols 2048..4095.
// y overwrites u in place (per-element RAW-safe).
__global__ __launch_bounds__(256) void ssm_scan(
    const float* __restrict__ xz,     // [bt,4096]: cols 0..2047 = delta, 2048..4095 = z
    float* uy,                        // in: u, out: y
    const float* __restrict__ proj,   // [bt,96]: cols 64..79 = B_in, 80..95 = C_in
    const float* __restrict__ A_log,
    const float* __restrict__ D_param)
{
    const int d = blockIdx.x * blockDim.x + threadIdx.x; // 0..2047
    const int b = blockIdx.y;

    float a[D_STATE];
#pragma unroll
    for (int s = 0; s < D_STATE; ++s)
        a[s] = -__expf(A_log[d * D_STATE + s]);
    const float Dp = D_param[d];

    float h[D_STATE];
#pragma unroll
    for (int s = 0; s < D_STATE; ++s) h[s] = 0.f;

    for (int t = 0; t < L_SEQ; ++t) {
        const size_t bt = (size_t)b * L_SEQ + t;
        const float dv = xz[bt * (2 * D_INNER) + d];
        const float uv = uy[bt * D_INNER + d];
        const float du = dv * uv;
        const float* pr = proj + bt * NPROJ;

        float acc = 0.f;
#pragma unroll
        for (int s = 0; s < D_STATE; ++s) {
            const float dA = __expf(dv * a[s]);
            h[s] = dA * h[s] + du * pr[DT_RANK + s];
            acc += h[s] * pr[DT_RANK + D_STATE + s];
        }
        float yv = acc + Dp * uv;

        const float zv = xz[bt * (2 * D_INNER) + D_INNER + d];
        const float gate = zv / (1.f + __expf(-zv));
        uy[bt * D_INNER + d] = yv * gate;
    }
}

extern "C" void kernel_launch(void* const* d_in, const int* in_sizes, int n_in,
                              void* d_out, int out_size, void* d_ws, size_t ws_size,
                              hipStream_t stream)
{
    // ALL inputs are float32 per the reference setup_inputs()
    const float* x         = (const float*)d_in[0];
    const float* in_proj_w = (const float*)d_in[1];
    const float* conv_w    = (const float*)d_in[2];
    const float* conv_b    = (const float*)d_in[3];
    const float* x_proj_w  = (const float*)d_in[4];
    const float* dt_proj_w = (const float*)d_in[5];
    const float* dt_proj_b = (const float*)d_in[6];
    const float* A_log     = (const float*)d_in[7];
    const float* D_param   = (const float*)d_in[8];
    const float* out_proj_w= (const float*)d_in[9];
    float* out = (float*)d_out;

    // Workspace (fp32, 51.1 MB):
    //   xz   : [BL,4096] 33.55 MB  (cols 0..2047: x_br, later overwritten by delta; 2048..4095: z)
    //   u/y  : [BL,2048] 16.78 MB  (u, overwritten in-place by y during scan)
    //   proj : [BL,  96]  0.79 MB
    float* xz   = (float*)d_ws;
    float* uy   = xz + (size_t)BL * 4096;
    float* proj = uy + (size_t)BL * 2048;

    dim3 blk(256);

    // 1. xz = x @ in_proj_w^T   (2048 x 4096 x 1024)
    gemm_btn<0><<<dim3((2 * D_INNER) / 64, BL / 64), blk, 0, stream>>>(
        x, D_MODEL, in_proj_w, D_MODEL, xz, 2 * D_INNER, BL, 2 * D_INNER, D_MODEL, nullptr);

    // 2. u = silu(causal_dwconv(x_br) + conv_b)
    conv_silu<<<(BL * D_INNER) / 256, blk, 0, stream>>>(xz, conv_w, conv_b, uy);

    // 3. proj = u @ x_proj_w^T  (2048 x 96 x 2048)
    gemm_btn<0><<<dim3((NPROJ + 63) / 64, BL / 64), blk, 0, stream>>>(
        uy, D_INNER, x_proj_w, D_INNER, proj, NPROJ, BL, NPROJ, D_INNER, nullptr);

    // 4. delta = softplus(proj[:,:64] @ dt_proj_w^T + dt_proj_b) (2048 x 2048 x 64)
    //    written into xz cols 0..2047 (x_br is dead after conv), ldc = 4096
    gemm_btn<1><<<dim3(D_INNER / 64, BL / 64), blk, 0, stream>>>(
        proj, NPROJ, dt_proj_w, DT_RANK, xz, 2 * D_INNER, BL, D_INNER, DT_RANK, dt_proj_b);

    // 5. SSM scan + D skip + silu(z) gate; writes y in-place over u
    ssm_scan<<<dim3(D_INNER / 256, B_SZ), blk, 0, stream>>>(
        xz, uy, proj, A_log, D_param);

    // 6. out = y @ out_proj_w^T (2048 x 1024 x 2048)
    gemm_btn<0><<<dim3(D_MODEL / 64, BL / 64), blk, 0, stream>>>(
        uy, D_INNER, out_proj_w, D_INNER, out, D_MODEL, BL, D_MODEL, D_INNER, nullptr);
}

// Round 4
// 916.459 us; speedup vs baseline: 1.5077x; 1.5077x over previous
//
#include <hip/hip_runtime.h>
#include <hip/hip_bf16.h>

#define D_MODEL 1024
#define D_INNER 2048
#define D_STATE 16
#define D_CONV  4
#define DT_RANK 64
#define B_SZ    2
#define L_SEQ   1024
#define BL      (B_SZ * L_SEQ)          // 2048 rows
#define NPROJ   (DT_RANK + 2 * D_STATE) // 96
#define CS      64                      // scan chunk size
#define NC      (L_SEQ / CS)            // 16 chunks

// C[M,N] = A[M,K] @ B[N,K]^T  (all fp32; B row-major as stored weight [N,K])
// EPI: 0 = none, 1 = softplus(acc + bias[n])
template <int EPI>
__global__ __launch_bounds__(256) void gemm_btn(
    const float* __restrict__ A, int lda,
    const float* __restrict__ Bw, int ldb,
    float* __restrict__ C, int ldc,
    int M, int N, int K,
    const float* __restrict__ bias)
{
    __shared__ float As[16][65];
    __shared__ float Bs[16][65];

    const int tid = threadIdx.x;
    const int bm = blockIdx.y * 64;
    const int bn = blockIdx.x * 64;

    const int tx = tid & 15;   // n-tile lane (x4)
    const int ty = tid >> 4;   // m-tile lane (x4)

    const int lrow = tid >> 2; // 0..63 : row within tile for staging
    const int lcg  = tid & 3;  // 0..3  : k-group (x4) for staging

    float acc[4][4];
#pragma unroll
    for (int i = 0; i < 4; ++i)
#pragma unroll
        for (int j = 0; j < 4; ++j) acc[i][j] = 0.f;

    for (int k0 = 0; k0 < K; k0 += 16) {
        {
            const int ar = bm + lrow;
            float4 v = make_float4(0.f, 0.f, 0.f, 0.f);
            if (ar < M)
                v = *(const float4*)(A + (size_t)ar * lda + k0 + lcg * 4);
            As[lcg * 4 + 0][lrow] = v.x;
            As[lcg * 4 + 1][lrow] = v.y;
            As[lcg * 4 + 2][lrow] = v.z;
            As[lcg * 4 + 3][lrow] = v.w;
        }
        {
            const int br = bn + lrow;
            float4 v = make_float4(0.f, 0.f, 0.f, 0.f);
            if (br < N)
                v = *(const float4*)(Bw + (size_t)br * ldb + k0 + lcg * 4);
            Bs[lcg * 4 + 0][lrow] = v.x;
            Bs[lcg * 4 + 1][lrow] = v.y;
            Bs[lcg * 4 + 2][lrow] = v.z;
            Bs[lcg * 4 + 3][lrow] = v.w;
        }
        __syncthreads();

#pragma unroll
        for (int kk = 0; kk < 16; ++kk) {
            float a[4], b[4];
#pragma unroll
            for (int i = 0; i < 4; ++i) a[i] = As[kk][ty * 4 + i];
#pragma unroll
            for (int j = 0; j < 4; ++j) b[j] = Bs[kk][tx * 4 + j];
#pragma unroll
            for (int i = 0; i < 4; ++i)
#pragma unroll
                for (int j = 0; j < 4; ++j) acc[i][j] += a[i] * b[j];
        }
        __syncthreads();
    }

#pragma unroll
    for (int i = 0; i < 4; ++i) {
        const int m = bm + ty * 4 + i;
        if (m >= M) continue;
#pragma unroll
        for (int j = 0; j < 4; ++j) {
            const int n = bn + tx * 4 + j;
            if (n >= N) continue;
            float v = acc[i][j];
            if (EPI == 1) {
                v += bias[n];
                v = (v > 20.f) ? v : log1pf(__expf(v));
            }
            C[(size_t)m * ldc + n] = v;
        }
    }
}

// depthwise causal conv1d + bias + SiLU. xz layout: [(b*L+t), 4096]; x_br = cols 0..2047
__global__ __launch_bounds__(256) void conv_silu(
    const float* __restrict__ xz,
    const float* __restrict__ conv_w,
    const float* __restrict__ conv_b,
    float* __restrict__ u)
{
    const int idx = blockIdx.x * blockDim.x + threadIdx.x; // (b*L+t)*2048 + d
    const int d  = idx & (D_INNER - 1);
    const int bt = idx >> 11;          // b*L + t
    const int t  = bt & (L_SEQ - 1);

    const float w0 = conv_w[d * 4 + 0];
    const float w1 = conv_w[d * 4 + 1];
    const float w2 = conv_w[d * 4 + 2];
    const float w3 = conv_w[d * 4 + 3];

    const float* col = xz + (size_t)bt * (2 * D_INNER) + d;
    float acc = conv_b[d];
    if (t >= 3) acc += col[-3 * 2 * D_INNER] * w0;
    if (t >= 2) acc += col[-2 * 2 * D_INNER] * w1;
    if (t >= 1) acc += col[-1 * 2 * D_INNER] * w2;
    acc += col[0] * w3;

    const float s = acc / (1.f + __expf(-acc)); // silu
    u[idx] = s;
}

// ---- chunked associative scan ----------------------------------------------
// delta lives in xz cols 0..2047 (stride 4096); z in cols 2048..4095.
// hloc/carry layout: [((b*NC + c)*D_STATE + s)*D_INNER + d]  (coalesced in d)
// sumd layout:       [(b*NC + c)*D_INNER + d]

// Phase A: chunk-local scan from h=0; emit final local state + sum(delta).
__global__ __launch_bounds__(256) void scan_phase_a(
    const float* __restrict__ xz,
    const float* __restrict__ u,
    const float* __restrict__ proj,
    const float* __restrict__ A_log,
    float* __restrict__ hloc,
    float* __restrict__ sumd)
{
    const int d = blockIdx.x * 256 + threadIdx.x;
    const int c = blockIdx.y;
    const int b = blockIdx.z;

    float a[D_STATE];
#pragma unroll
    for (int s = 0; s < D_STATE; ++s) a[s] = -__expf(A_log[d * D_STATE + s]);

    float h[D_STATE];
#pragma unroll
    for (int s = 0; s < D_STATE; ++s) h[s] = 0.f;
    float sd = 0.f;

    for (int t = c * CS; t < (c + 1) * CS; ++t) {
        const size_t bt = (size_t)b * L_SEQ + t;
        const float dv = xz[bt * (2 * D_INNER) + d];
        const float uv = u[bt * D_INNER + d];
        const float du = dv * uv;
        sd += dv;
        const float* pr = proj + bt * NPROJ;
#pragma unroll
        for (int s = 0; s < D_STATE; ++s)
            h[s] = __expf(dv * a[s]) * h[s] + du * pr[DT_RANK + s];
    }

    const size_t base = ((size_t)(b * NC + c) * D_STATE) * D_INNER + d;
#pragma unroll
    for (int s = 0; s < D_STATE; ++s) hloc[base + (size_t)s * D_INNER] = h[s];
    sumd[(size_t)(b * NC + c) * D_INNER + d] = sd;
}

// Phase B: sequential combine over chunks -> carry-in state per chunk.
// Chunk decay product P[s] = exp(a[s] * sum(delta over chunk)).
__global__ __launch_bounds__(256) void scan_phase_b(
    const float* __restrict__ hloc,
    const float* __restrict__ sumd,
    const float* __restrict__ A_log,
    float* __restrict__ carry)
{
    const int d = blockIdx.x * 256 + threadIdx.x;
    const int b = blockIdx.y;

    float a[D_STATE];
#pragma unroll
    for (int s = 0; s < D_STATE; ++s) a[s] = -__expf(A_log[d * D_STATE + s]);

    float hc[D_STATE];
#pragma unroll
    for (int s = 0; s < D_STATE; ++s) {
        hc[s] = 0.f;
        carry[((size_t)(b * NC + 0) * D_STATE + s) * D_INNER + d] = 0.f;
    }

    for (int c = 1; c < NC; ++c) {
        const float sd = sumd[(size_t)(b * NC + c - 1) * D_INNER + d];
        const size_t pbase = ((size_t)(b * NC + c - 1) * D_STATE) * D_INNER + d;
        const size_t cbase = ((size_t)(b * NC + c) * D_STATE) * D_INNER + d;
#pragma unroll
        for (int s = 0; s < D_STATE; ++s) {
            const float P = __expf(a[s] * sd);
            hc[s] = P * hc[s] + hloc[pbase + (size_t)s * D_INNER];
            carry[cbase + (size_t)s * D_INNER] = hc[s];
        }
    }
}

// Phase C: re-run chunk with true carry-in; y + D skip + silu(z) gate, in-place over u.
__global__ __launch_bounds__(256) void scan_phase_c(
    const float* __restrict__ xz,
    float* uy,                        // in: u, out: y (per-element RAW-safe)
    const float* __restrict__ proj,
    const float* __restrict__ A_log,
    const float* __restrict__ D_param,
    const float* __restrict__ carry)
{
    const int d = blockIdx.x * 256 + threadIdx.x;
    const int c = blockIdx.y;
    const int b = blockIdx.z;

    float a[D_STATE];
#pragma unroll
    for (int s = 0; s < D_STATE; ++s) a[s] = -__expf(A_log[d * D_STATE + s]);
    const float Dp = D_param[d];

    float h[D_STATE];
    const size_t cbase = ((size_t)(b * NC + c) * D_STATE) * D_INNER + d;
#pragma unroll
    for (int s = 0; s < D_STATE; ++s) h[s] = carry[cbase + (size_t)s * D_INNER];

    for (int t = c * CS; t < (c + 1) * CS; ++t) {
        const size_t bt = (size_t)b * L_SEQ + t;
        const float dv = xz[bt * (2 * D_INNER) + d];
        const float uv = uy[bt * D_INNER + d];
        const float du = dv * uv;
        const float* pr = proj + bt * NPROJ;

        float acc = 0.f;
#pragma unroll
        for (int s = 0; s < D_STATE; ++s) {
            h[s] = __expf(dv * a[s]) * h[s] + du * pr[DT_RANK + s];
            acc += h[s] * pr[DT_RANK + D_STATE + s];
        }
        const float yv = acc + Dp * uv;

        const float zv = xz[bt * (2 * D_INNER) + D_INNER + d];
        const float gate = zv / (1.f + __expf(-zv));
        uy[bt * D_INNER + d] = yv * gate;
    }
}

extern "C" void kernel_launch(void* const* d_in, const int* in_sizes, int n_in,
                              void* d_out, int out_size, void* d_ws, size_t ws_size,
                              hipStream_t stream)
{
    // ALL inputs are float32 per the reference setup_inputs()
    const float* x         = (const float*)d_in[0];
    const float* in_proj_w = (const float*)d_in[1];
    const float* conv_w    = (const float*)d_in[2];
    const float* conv_b    = (const float*)d_in[3];
    const float* x_proj_w  = (const float*)d_in[4];
    const float* dt_proj_w = (const float*)d_in[5];
    const float* dt_proj_b = (const float*)d_in[6];
    const float* A_log     = (const float*)d_in[7];
    const float* D_param   = (const float*)d_in[8];
    const float* out_proj_w= (const float*)d_in[9];
    float* out = (float*)d_out;

    // Workspace (fp32, ~59.5 MB):
    //   xz    : [BL,4096]          33.55 MB (cols 0..2047: x_br -> delta; 2048..4095: z)
    //   u/y   : [BL,2048]          16.78 MB
    //   proj  : [BL,96]             0.79 MB
    //   hloc  : [B,NC,16,D_INNER]   4.19 MB
    //   carry : [B,NC,16,D_INNER]   4.19 MB
    //   sumd  : [B,NC,D_INNER]      0.26 MB
    float* xz    = (float*)d_ws;
    float* uy    = xz    + (size_t)BL * 4096;
    float* proj  = uy    + (size_t)BL * 2048;
    float* hloc  = proj  + (size_t)BL * NPROJ;
    float* carry = hloc  + (size_t)B_SZ * NC * D_STATE * D_INNER;
    float* sumd  = carry + (size_t)B_SZ * NC * D_STATE * D_INNER;

    dim3 blk(256);

    // 1. xz = x @ in_proj_w^T   (2048 x 4096 x 1024)
    gemm_btn<0><<<dim3((2 * D_INNER) / 64, BL / 64), blk, 0, stream>>>(
        x, D_MODEL, in_proj_w, D_MODEL, xz, 2 * D_INNER, BL, 2 * D_INNER, D_MODEL, nullptr);

    // 2. u = silu(causal_dwconv(x_br) + conv_b)
    conv_silu<<<(BL * D_INNER) / 256, blk, 0, stream>>>(xz, conv_w, conv_b, uy);

    // 3. proj = u @ x_proj_w^T  (2048 x 96 x 2048)
    gemm_btn<0><<<dim3((NPROJ + 63) / 64, BL / 64), blk, 0, stream>>>(
        uy, D_INNER, x_proj_w, D_INNER, proj, NPROJ, BL, NPROJ, D_INNER, nullptr);

    // 4. delta = softplus(proj[:,:64] @ dt_proj_w^T + dt_proj_b), into xz cols 0..2047
    gemm_btn<1><<<dim3(D_INNER / 64, BL / 64), blk, 0, stream>>>(
        proj, NPROJ, dt_proj_w, DT_RANK, xz, 2 * D_INNER, BL, D_INNER, DT_RANK, dt_proj_b);

    // 5. chunked SSM scan (3 phases) + D skip + silu(z) gate; y in-place over u
    scan_phase_a<<<dim3(D_INNER / 256, NC, B_SZ), blk, 0, stream>>>(
        xz, uy, proj, A_log, hloc, sumd);
    scan_phase_b<<<dim3(D_INNER / 256, B_SZ), blk, 0, stream>>>(
        hloc, sumd, A_log, carry);
    scan_phase_c<<<dim3(D_INNER / 256, NC, B_SZ), blk, 0, stream>>>(
        xz, uy, proj, A_log, D_param, carry);

    // 6. out = y @ out_proj_w^T (2048 x 1024 x 2048)
    gemm_btn<0><<<dim3(D_MODEL / 64, BL / 64), blk, 0, stream>>>(
        uy, D_INNER, out_proj_w, D_INNER, out, D_MODEL, BL, D_MODEL, D_INNER, nullptr);
}

// Round 5
// 517.294 us; speedup vs baseline: 2.6710x; 1.7716x over previous
//
#include <hip/hip_runtime.h>
#include <hip/hip_bf16.h>

#define D_MODEL 1024
#define D_INNER 2048
#define D_STATE 16
#define D_CONV  4
#define DT_RANK 64
#define B_SZ    2
#define L_SEQ   1024
#define BL      (B_SZ * L_SEQ)          // 2048 rows
#define NPROJ   (DT_RANK + 2 * D_STATE) // 96
#define CS      64                      // scan chunk size
#define NC      (L_SEQ / CS)            // 16 chunks

typedef __attribute__((ext_vector_type(8))) short bf16x8;
typedef __attribute__((ext_vector_type(4))) float floatx4;

// ---------------- split-bf16 MFMA GEMM -------------------------------------
// C[M,N] = A[M,K] @ B[N,K]^T, fp32 in/out, hi/lo bf16 decomposition on the fly.
// Tile: 128 x TN, BK=32, 256 threads = 4 waves, each wave 64 x (TN/2).
// MFMA 16x16x32 bf16; verified layouts:
//   A-frag: A[m=lane&15][k=(lane>>4)*8+j]   B-frag: B[n=lane&15][k=(lane>>4)*8+j]
//   D:      D[row=(lane>>4)*4+reg][col=lane&15]

__device__ __forceinline__ void mfma_bf16(floatx4& acc, bf16x8 a, bf16x8 b) {
    asm volatile("v_mfma_f32_16x16x32_bf16 %0, %1, %2, %0"
                 : "+v"(acc) : "v"(a), "v"(b));
}

__device__ __forceinline__ uint4 pack8(const short* s) {
    uint4 u;
    u.x = (unsigned)(unsigned short)s[0] | ((unsigned)(unsigned short)s[1] << 16);
    u.y = (unsigned)(unsigned short)s[2] | ((unsigned)(unsigned short)s[3] << 16);
    u.z = (unsigned)(unsigned short)s[4] | ((unsigned)(unsigned short)s[5] << 16);
    u.w = (unsigned)(unsigned short)s[6] | ((unsigned)(unsigned short)s[7] << 16);
    return u;
}

__device__ __forceinline__ void cvt_hilo(float f, short& hi, short& lo) {
    __hip_bfloat16 h = __float2bfloat16(f);
    hi = *(short*)&h;
    __hip_bfloat16 l = __float2bfloat16(f - __bfloat162float(h));
    lo = *(short*)&l;
}

__device__ __forceinline__ void stage16(const float* __restrict__ g,
                                        short* hi_dst, short* lo_dst) {
    float f[16];
#pragma unroll
    for (int i = 0; i < 4; ++i) {
        float4 v = ((const float4*)g)[i];
        f[i*4+0] = v.x; f[i*4+1] = v.y; f[i*4+2] = v.z; f[i*4+3] = v.w;
    }
    short hi[16], lo[16];
#pragma unroll
    for (int i = 0; i < 16; ++i) cvt_hilo(f[i], hi[i], lo[i]);
    ((uint4*)hi_dst)[0] = pack8(hi);
    ((uint4*)hi_dst)[1] = pack8(hi + 8);
    ((uint4*)lo_dst)[0] = pack8(lo);
    ((uint4*)lo_dst)[1] = pack8(lo + 8);
}

__device__ __forceinline__ void stage8(const float* __restrict__ g,
                                       short* hi_dst, short* lo_dst) {
    float f[8];
#pragma unroll
    for (int i = 0; i < 2; ++i) {
        float4 v = ((const float4*)g)[i];
        f[i*4+0] = v.x; f[i*4+1] = v.y; f[i*4+2] = v.z; f[i*4+3] = v.w;
    }
    short hi[8], lo[8];
#pragma unroll
    for (int i = 0; i < 8; ++i) cvt_hilo(f[i], hi[i], lo[i]);
    ((uint4*)hi_dst)[0] = pack8(hi);
    ((uint4*)lo_dst)[0] = pack8(lo);
}

template <int TN>  // TN in {128, 64}; M%128==0, N%TN==0, K%32==0 assumed
__global__ __launch_bounds__(256, 2) void gemm_mfma(
    const float* __restrict__ A, int lda,
    const float* __restrict__ Bw, int ldb,
    float* __restrict__ C, int ldc, int K)
{
    __shared__ __align__(16) short As[2][128 * 32];
    __shared__ __align__(16) short Bs[2][TN * 32];

    const int tid = threadIdx.x;
    const int bm = blockIdx.y * 128;
    const int bn = blockIdx.x * TN;

    const int wave = tid >> 6;
    const int lane = tid & 63;
    const int wm = (wave >> 1) * 64;
    const int wn = (wave & 1) * (TN / 2);
    const int ml = lane & 15;
    const int q  = lane >> 4;
    constexpr int JT = TN / 32;   // n-tiles of 16 per wave

    floatx4 acc[4][JT];
#pragma unroll
    for (int i = 0; i < 4; ++i)
#pragma unroll
        for (int j = 0; j < JT; ++j) acc[i][j] = (floatx4)0.f;

    const int ar  = tid >> 1;          // 0..127
    const int akh = (tid & 1) * 16;    // 0 / 16

    for (int k0 = 0; k0 < K; k0 += 32) {
        __syncthreads();
        // stage A tile (128 x 32) as hi/lo bf16
        stage16(A + (size_t)(bm + ar) * lda + k0 + akh,
                &As[0][ar * 32 + akh], &As[1][ar * 32 + akh]);
        // stage B tile (TN x 32)
        if (TN == 128) {
            stage16(Bw + (size_t)(bn + ar) * ldb + k0 + akh,
                    &Bs[0][ar * 32 + akh], &Bs[1][ar * 32 + akh]);
        } else {
            const int br  = tid >> 2;         // 0..63
            const int bkq = (tid & 3) * 8;    // 0,8,16,24
            stage8(Bw + (size_t)(bn + br) * ldb + k0 + bkq,
                   &Bs[0][br * 32 + bkq], &Bs[1][br * 32 + bkq]);
        }
        __syncthreads();

        bf16x8 ah[4], al[4], bh[JT], bl[JT];
#pragma unroll
        for (int i = 0; i < 4; ++i) {
            const int r = wm + i * 16 + ml;
            ah[i] = *(const bf16x8*)&As[0][r * 32 + q * 8];
            al[i] = *(const bf16x8*)&As[1][r * 32 + q * 8];
        }
#pragma unroll
        for (int j = 0; j < JT; ++j) {
            const int r = wn + j * 16 + ml;
            bh[j] = *(const bf16x8*)&Bs[0][r * 32 + q * 8];
            bl[j] = *(const bf16x8*)&Bs[1][r * 32 + q * 8];
        }
#pragma unroll
        for (int i = 0; i < 4; ++i)
#pragma unroll
            for (int j = 0; j < JT; ++j) {
                mfma_bf16(acc[i][j], ah[i], bh[j]);
                mfma_bf16(acc[i][j], ah[i], bl[j]);
                mfma_bf16(acc[i][j], al[i], bh[j]);
            }
    }

    // drain MFMA pipe before VALU reads of acc (inline asm hides the dep)
    asm volatile("s_nop 7\n\ts_nop 7\n\ts_nop 7" ::: "memory");

#pragma unroll
    for (int i = 0; i < 4; ++i)
#pragma unroll
        for (int j = 0; j < JT; ++j)
#pragma unroll
            for (int r = 0; r < 4; ++r) {
                const int row = bm + wm + i * 16 + q * 4 + r;
                const int col = bn + wn + j * 16 + ml;
                C[(size_t)row * ldc + col] = acc[i][j][r];
            }
}

// ---------------- fp32 VALU GEMM (small shapes) ----------------------------
// EPI: 0 = none, 1 = softplus(acc + bias[n])
template <int EPI>
__global__ __launch_bounds__(256) void gemm_btn(
    const float* __restrict__ A, int lda,
    const float* __restrict__ Bw, int ldb,
    float* __restrict__ C, int ldc,
    int M, int N, int K,
    const float* __restrict__ bias)
{
    __shared__ float As[16][65];
    __shared__ float Bs[16][65];

    const int tid = threadIdx.x;
    const int bm = blockIdx.y * 64;
    const int bn = blockIdx.x * 64;

    const int tx = tid & 15;
    const int ty = tid >> 4;
    const int lrow = tid >> 2;
    const int lcg  = tid & 3;

    float acc[4][4];
#pragma unroll
    for (int i = 0; i < 4; ++i)
#pragma unroll
        for (int j = 0; j < 4; ++j) acc[i][j] = 0.f;

    for (int k0 = 0; k0 < K; k0 += 16) {
        {
            const int ar = bm + lrow;
            float4 v = make_float4(0.f, 0.f, 0.f, 0.f);
            if (ar < M)
                v = *(const float4*)(A + (size_t)ar * lda + k0 + lcg * 4);
            As[lcg * 4 + 0][lrow] = v.x;
            As[lcg * 4 + 1][lrow] = v.y;
            As[lcg * 4 + 2][lrow] = v.z;
            As[lcg * 4 + 3][lrow] = v.w;
        }
        {
            const int br = bn + lrow;
            float4 v = make_float4(0.f, 0.f, 0.f, 0.f);
            if (br < N)
                v = *(const float4*)(Bw + (size_t)br * ldb + k0 + lcg * 4);
            Bs[lcg * 4 + 0][lrow] = v.x;
            Bs[lcg * 4 + 1][lrow] = v.y;
            Bs[lcg * 4 + 2][lrow] = v.z;
            Bs[lcg * 4 + 3][lrow] = v.w;
        }
        __syncthreads();

#pragma unroll
        for (int kk = 0; kk < 16; ++kk) {
            float a[4], b[4];
#pragma unroll
            for (int i = 0; i < 4; ++i) a[i] = As[kk][ty * 4 + i];
#pragma unroll
            for (int j = 0; j < 4; ++j) b[j] = Bs[kk][tx * 4 + j];
#pragma unroll
            for (int i = 0; i < 4; ++i)
#pragma unroll
                for (int j = 0; j < 4; ++j) acc[i][j] += a[i] * b[j];
        }
        __syncthreads();
    }

#pragma unroll
    for (int i = 0; i < 4; ++i) {
        const int m = bm + ty * 4 + i;
        if (m >= M) continue;
#pragma unroll
        for (int j = 0; j < 4; ++j) {
            const int n = bn + tx * 4 + j;
            if (n >= N) continue;
            float v = acc[i][j];
            if (EPI == 1) {
                v += bias[n];
                v = (v > 20.f) ? v : log1pf(__expf(v));
            }
            C[(size_t)m * ldc + n] = v;
        }
    }
}

// depthwise causal conv1d + bias + SiLU
__global__ __launch_bounds__(256) void conv_silu(
    const float* __restrict__ xz,
    const float* __restrict__ conv_w,
    const float* __restrict__ conv_b,
    float* __restrict__ u)
{
    const int idx = blockIdx.x * blockDim.x + threadIdx.x;
    const int d  = idx & (D_INNER - 1);
    const int bt = idx >> 11;
    const int t  = bt & (L_SEQ - 1);

    const float w0 = conv_w[d * 4 + 0];
    const float w1 = conv_w[d * 4 + 1];
    const float w2 = conv_w[d * 4 + 2];
    const float w3 = conv_w[d * 4 + 3];

    const float* col = xz + (size_t)bt * (2 * D_INNER) + d;
    float acc = conv_b[d];
    if (t >= 3) acc += col[-3 * 2 * D_INNER] * w0;
    if (t >= 2) acc += col[-2 * 2 * D_INNER] * w1;
    if (t >= 1) acc += col[-1 * 2 * D_INNER] * w2;
    acc += col[0] * w3;

    u[idx] = acc / (1.f + __expf(-acc));
}

// ---- chunked associative scan ---------------------------------------------
__global__ __launch_bounds__(256) void scan_phase_a(
    const float* __restrict__ xz,
    const float* __restrict__ u,
    const float* __restrict__ proj,
    const float* __restrict__ A_log,
    float* __restrict__ hloc,
    float* __restrict__ sumd)
{
    const int d = blockIdx.x * 256 + threadIdx.x;
    const int c = blockIdx.y;
    const int b = blockIdx.z;

    float a[D_STATE];
#pragma unroll
    for (int s = 0; s < D_STATE; ++s) a[s] = -__expf(A_log[d * D_STATE + s]);

    float h[D_STATE];
#pragma unroll
    for (int s = 0; s < D_STATE; ++s) h[s] = 0.f;
    float sd = 0.f;

    for (int t = c * CS; t < (c + 1) * CS; ++t) {
        const size_t bt = (size_t)b * L_SEQ + t;
        const float dv = xz[bt * (2 * D_INNER) + d];
        const float uv = u[bt * D_INNER + d];
        const float du = dv * uv;
        sd += dv;
        const float* pr = proj + bt * NPROJ;
#pragma unroll
        for (int s = 0; s < D_STATE; ++s)
            h[s] = __expf(dv * a[s]) * h[s] + du * pr[DT_RANK + s];
    }

    const size_t base = ((size_t)(b * NC + c) * D_STATE) * D_INNER + d;
#pragma unroll
    for (int s = 0; s < D_STATE; ++s) hloc[base + (size_t)s * D_INNER] = h[s];
    sumd[(size_t)(b * NC + c) * D_INNER + d] = sd;
}

__global__ __launch_bounds__(256) void scan_phase_b(
    const float* __restrict__ hloc,
    const float* __restrict__ sumd,
    const float* __restrict__ A_log,
    float* __restrict__ carry)
{
    const int d = blockIdx.x * 256 + threadIdx.x;
    const int b = blockIdx.y;

    float a[D_STATE];
#pragma unroll
    for (int s = 0; s < D_STATE; ++s) a[s] = -__expf(A_log[d * D_STATE + s]);

    float hc[D_STATE];
#pragma unroll
    for (int s = 0; s < D_STATE; ++s) {
        hc[s] = 0.f;
        carry[((size_t)(b * NC + 0) * D_STATE + s) * D_INNER + d] = 0.f;
    }

    for (int c = 1; c < NC; ++c) {
        const float sd = sumd[(size_t)(b * NC + c - 1) * D_INNER + d];
        const size_t pbase = ((size_t)(b * NC + c - 1) * D_STATE) * D_INNER + d;
        const size_t cbase = ((size_t)(b * NC + c) * D_STATE) * D_INNER + d;
#pragma unroll
        for (int s = 0; s < D_STATE; ++s) {
            const float P = __expf(a[s] * sd);
            hc[s] = P * hc[s] + hloc[pbase + (size_t)s * D_INNER];
            carry[cbase + (size_t)s * D_INNER] = hc[s];
        }
    }
}

__global__ __launch_bounds__(256) void scan_phase_c(
    const float* __restrict__ xz,
    float* uy,
    const float* __restrict__ proj,
    const float* __restrict__ A_log,
    const float* __restrict__ D_param,
    const float* __restrict__ carry)
{
    const int d = blockIdx.x * 256 + threadIdx.x;
    const int c = blockIdx.y;
    const int b = blockIdx.z;

    float a[D_STATE];
#pragma unroll
    for (int s = 0; s < D_STATE; ++s) a[s] = -__expf(A_log[d * D_STATE + s]);
    const float Dp = D_param[d];

    float h[D_STATE];
    const size_t cbase = ((size_t)(b * NC + c) * D_STATE) * D_INNER + d;
#pragma unroll
    for (int s = 0; s < D_STATE; ++s) h[s] = carry[cbase + (size_t)s * D_INNER];

    for (int t = c * CS; t < (c + 1) * CS; ++t) {
        const size_t bt = (size_t)b * L_SEQ + t;
        const float dv = xz[bt * (2 * D_INNER) + d];
        const float uv = uy[bt * D_INNER + d];
        const float du = dv * uv;
        const float* pr = proj + bt * NPROJ;

        float acc = 0.f;
#pragma unroll
        for (int s = 0; s < D_STATE; ++s) {
            h[s] = __expf(dv * a[s]) * h[s] + du * pr[DT_RANK + s];
            acc += h[s] * pr[DT_RANK + D_STATE + s];
        }
        const float yv = acc + Dp * uv;

        const float zv = xz[bt * (2 * D_INNER) + D_INNER + d];
        const float gate = zv / (1.f + __expf(-zv));
        uy[bt * D_INNER + d] = yv * gate;
    }
}

extern "C" void kernel_launch(void* const* d_in, const int* in_sizes, int n_in,
                              void* d_out, int out_size, void* d_ws, size_t ws_size,
                              hipStream_t stream)
{
    const float* x         = (const float*)d_in[0];
    const float* in_proj_w = (const float*)d_in[1];
    const float* conv_w    = (const float*)d_in[2];
    const float* conv_b    = (const float*)d_in[3];
    const float* x_proj_w  = (const float*)d_in[4];
    const float* dt_proj_w = (const float*)d_in[5];
    const float* dt_proj_b = (const float*)d_in[6];
    const float* A_log     = (const float*)d_in[7];
    const float* D_param   = (const float*)d_in[8];
    const float* out_proj_w= (const float*)d_in[9];
    float* out = (float*)d_out;

    float* xz    = (float*)d_ws;                    // [BL,4096] x_br->delta | z
    float* uy    = xz    + (size_t)BL * 4096;       // [BL,2048] u -> y
    float* proj  = uy    + (size_t)BL * 2048;       // [BL,96]
    float* hloc  = proj  + (size_t)BL * NPROJ;
    float* carry = hloc  + (size_t)B_SZ * NC * D_STATE * D_INNER;
    float* sumd  = carry + (size_t)B_SZ * NC * D_STATE * D_INNER;

    dim3 blk(256);

    // 1. xz = x @ in_proj_w^T   (2048 x 4096 x 1024)  [split-bf16 MFMA]
    gemm_mfma<128><<<dim3((2 * D_INNER) / 128, BL / 128), blk, 0, stream>>>(
        x, D_MODEL, in_proj_w, D_MODEL, xz, 2 * D_INNER, D_MODEL);

    // 2. u = silu(causal_dwconv(x_br) + conv_b)
    conv_silu<<<(BL * D_INNER) / 256, blk, 0, stream>>>(xz, conv_w, conv_b, uy);

    // 3. proj = u @ x_proj_w^T  (2048 x 96 x 2048)
    gemm_btn<0><<<dim3((NPROJ + 63) / 64, BL / 64), blk, 0, stream>>>(
        uy, D_INNER, x_proj_w, D_INNER, proj, NPROJ, BL, NPROJ, D_INNER, nullptr);

    // 4. delta = softplus(proj[:,:64] @ dt_proj_w^T + dt_proj_b), into xz cols 0..2047
    gemm_btn<1><<<dim3(D_INNER / 64, BL / 64), blk, 0, stream>>>(
        proj, NPROJ, dt_proj_w, DT_RANK, xz, 2 * D_INNER, BL, D_INNER, DT_RANK, dt_proj_b);

    // 5. chunked SSM scan (3 phases) + D skip + silu(z) gate; y in-place over u
    scan_phase_a<<<dim3(D_INNER / 256, NC, B_SZ), blk, 0, stream>>>(
        xz, uy, proj, A_log, hloc, sumd);
    scan_phase_b<<<dim3(D_INNER / 256, B_SZ), blk, 0, stream>>>(
        hloc, sumd, A_log, carry);
    scan_phase_c<<<dim3(D_INNER / 256, NC, B_SZ), blk, 0, stream>>>(
        xz, uy, proj, A_log, D_param, carry);

    // 6. out = y @ out_proj_w^T (2048 x 1024 x 2048)  [split-bf16 MFMA, 128x64 tile]
    gemm_mfma<64><<<dim3(D_MODEL / 64, BL / 128), blk, 0, stream>>>(
        uy, D_INNER, out_proj_w, D_INNER, out, D_MODEL, D_INNER);
}

// Round 6
// 391.122 us; speedup vs baseline: 3.5327x; 1.3226x over previous
//
#include <hip/hip_runtime.h>
#include <hip/hip_bf16.h>

#define D_MODEL 1024
#define D_INNER 2048
#define D_STATE 16
#define D_CONV  4
#define DT_RANK 64
#define B_SZ    2
#define L_SEQ   1024
#define BL      (B_SZ * L_SEQ)          // 2048 rows
#define NPROJ   (DT_RANK + 2 * D_STATE) // 96
#define CS      64                      // scan chunk size
#define NC      (L_SEQ / CS)            // 16 chunks

typedef __attribute__((ext_vector_type(8))) short bf16x8;
typedef __attribute__((ext_vector_type(4))) float floatx4;

// ---------------- split-bf16 MFMA GEMM -------------------------------------
// C[M,N] = A[M,K] @ B[N,K]^T, fp32 in/out, hi/lo bf16 decomposition on the fly.
// Tile: 128 x TN, BK=32, 256 threads = 4 waves, each wave 64 x (TN/2).
// EPI: 0 = none, 1 = softplus(acc + bias[col])

__device__ __forceinline__ void mfma_bf16(floatx4& acc, bf16x8 a, bf16x8 b) {
    asm volatile("v_mfma_f32_16x16x32_bf16 %0, %1, %2, %0"
                 : "+v"(acc) : "v"(a), "v"(b));
}

__device__ __forceinline__ uint4 pack8(const short* s) {
    uint4 u;
    u.x = (unsigned)(unsigned short)s[0] | ((unsigned)(unsigned short)s[1] << 16);
    u.y = (unsigned)(unsigned short)s[2] | ((unsigned)(unsigned short)s[3] << 16);
    u.z = (unsigned)(unsigned short)s[4] | ((unsigned)(unsigned short)s[5] << 16);
    u.w = (unsigned)(unsigned short)s[6] | ((unsigned)(unsigned short)s[7] << 16);
    return u;
}

__device__ __forceinline__ void cvt_hilo(float f, short& hi, short& lo) {
    __hip_bfloat16 h = __float2bfloat16(f);
    hi = *(short*)&h;
    __hip_bfloat16 l = __float2bfloat16(f - __bfloat162float(h));
    lo = *(short*)&l;
}

__device__ __forceinline__ void stage16(const float* __restrict__ g,
                                        short* hi_dst, short* lo_dst) {
    float f[16];
#pragma unroll
    for (int i = 0; i < 4; ++i) {
        float4 v = ((const float4*)g)[i];
        f[i*4+0] = v.x; f[i*4+1] = v.y; f[i*4+2] = v.z; f[i*4+3] = v.w;
    }
    short hi[16], lo[16];
#pragma unroll
    for (int i = 0; i < 16; ++i) cvt_hilo(f[i], hi[i], lo[i]);
    ((uint4*)hi_dst)[0] = pack8(hi);
    ((uint4*)hi_dst)[1] = pack8(hi + 8);
    ((uint4*)lo_dst)[0] = pack8(lo);
    ((uint4*)lo_dst)[1] = pack8(lo + 8);
}

__device__ __forceinline__ void stage8(const float* __restrict__ g,
                                       short* hi_dst, short* lo_dst) {
    float f[8];
#pragma unroll
    for (int i = 0; i < 2; ++i) {
        float4 v = ((const float4*)g)[i];
        f[i*4+0] = v.x; f[i*4+1] = v.y; f[i*4+2] = v.z; f[i*4+3] = v.w;
    }
    short hi[8], lo[8];
#pragma unroll
    for (int i = 0; i < 8; ++i) cvt_hilo(f[i], hi[i], lo[i]);
    ((uint4*)hi_dst)[0] = pack8(hi);
    ((uint4*)lo_dst)[0] = pack8(lo);
}

template <int TN, int EPI>  // TN in {128, 64}; M%128==0, N%TN==0, K%32==0
__global__ __launch_bounds__(256, 2) void gemm_mfma(
    const float* __restrict__ A, int lda,
    const float* __restrict__ Bw, int ldb,
    float* __restrict__ C, int ldc, int K,
    const float* __restrict__ bias)
{
    __shared__ __align__(16) short As[2][128 * 32];
    __shared__ __align__(16) short Bs[2][TN * 32];

    const int tid = threadIdx.x;
    const int bm = blockIdx.y * 128;
    const int bn = blockIdx.x * TN;

    const int wave = tid >> 6;
    const int lane = tid & 63;
    const int wm = (wave >> 1) * 64;
    const int wn = (wave & 1) * (TN / 2);
    const int ml = lane & 15;
    const int q  = lane >> 4;
    constexpr int JT = TN / 32;   // n-tiles of 16 per wave

    floatx4 acc[4][JT];
#pragma unroll
    for (int i = 0; i < 4; ++i)
#pragma unroll
        for (int j = 0; j < JT; ++j) acc[i][j] = (floatx4)0.f;

    const int ar  = tid >> 1;          // 0..127
    const int akh = (tid & 1) * 16;    // 0 / 16

    for (int k0 = 0; k0 < K; k0 += 32) {
        __syncthreads();
        stage16(A + (size_t)(bm + ar) * lda + k0 + akh,
                &As[0][ar * 32 + akh], &As[1][ar * 32 + akh]);
        if (TN == 128) {
            stage16(Bw + (size_t)(bn + ar) * ldb + k0 + akh,
                    &Bs[0][ar * 32 + akh], &Bs[1][ar * 32 + akh]);
        } else {
            const int br  = tid >> 2;         // 0..63
            const int bkq = (tid & 3) * 8;    // 0,8,16,24
            stage8(Bw + (size_t)(bn + br) * ldb + k0 + bkq,
                   &Bs[0][br * 32 + bkq], &Bs[1][br * 32 + bkq]);
        }
        __syncthreads();

        bf16x8 ah[4], al[4], bh[JT], bl[JT];
#pragma unroll
        for (int i = 0; i < 4; ++i) {
            const int r = wm + i * 16 + ml;
            ah[i] = *(const bf16x8*)&As[0][r * 32 + q * 8];
            al[i] = *(const bf16x8*)&As[1][r * 32 + q * 8];
        }
#pragma unroll
        for (int j = 0; j < JT; ++j) {
            const int r = wn + j * 16 + ml;
            bh[j] = *(const bf16x8*)&Bs[0][r * 32 + q * 8];
            bl[j] = *(const bf16x8*)&Bs[1][r * 32 + q * 8];
        }
#pragma unroll
        for (int i = 0; i < 4; ++i)
#pragma unroll
            for (int j = 0; j < JT; ++j) {
                mfma_bf16(acc[i][j], ah[i], bh[j]);
                mfma_bf16(acc[i][j], ah[i], bl[j]);
                mfma_bf16(acc[i][j], al[i], bh[j]);
            }
    }

    asm volatile("s_nop 7\n\ts_nop 7\n\ts_nop 7" ::: "memory");

#pragma unroll
    for (int i = 0; i < 4; ++i)
#pragma unroll
        for (int j = 0; j < JT; ++j)
#pragma unroll
            for (int r = 0; r < 4; ++r) {
                const int row = bm + wm + i * 16 + q * 4 + r;
                const int col = bn + wn + j * 16 + ml;
                float v = acc[i][j][r];
                if (EPI == 1) {
                    v += bias[col];
                    v = (v > 20.f) ? v : log1pf(__expf(v));
                }
                C[(size_t)row * ldc + col] = v;
            }
}

// ---------------- thin-N split-K GEMM for proj -----------------------------
// proj[BL,96] += u[BL,2048] @ Wp[96,2048]^T ; grid (KSPLIT=8, BL/64=32)
#define PKC 256   // K per block
#define PSC 64    // K sub-chunk staged in LDS

__global__ __launch_bounds__(256) void gemm_proj(
    const float* __restrict__ u,
    const float* __restrict__ Wp,
    float* __restrict__ proj)   // pre-zeroed
{
    __shared__ float us[PSC][65];    // [k][m]
    __shared__ float wsh[PSC][100];  // [k][n]

    const int tid = threadIdx.x;
    const int bm = blockIdx.y * 64;
    const int kbase0 = blockIdx.x * PKC;

    const int tx = tid & 15;
    const int ty = tid >> 4;

    float acc[4][6];
#pragma unroll
    for (int i = 0; i < 4; ++i)
#pragma unroll
        for (int j = 0; j < 6; ++j) acc[i][j] = 0.f;

    for (int sc = 0; sc < PKC / PSC; ++sc) {
        const int kb = kbase0 + sc * PSC;
        __syncthreads();
#pragma unroll
        for (int i = 0; i < 4; ++i) {           // u: 64 rows x 64 k
            const int flat = tid + 256 * i;
            const int r = flat >> 4;
            const int k4 = flat & 15;
            float4 v = *(const float4*)(u + (size_t)(bm + r) * D_INNER + kb + k4 * 4);
            us[k4*4+0][r] = v.x; us[k4*4+1][r] = v.y;
            us[k4*4+2][r] = v.z; us[k4*4+3][r] = v.w;
        }
#pragma unroll
        for (int i = 0; i < 6; ++i) {           // w: 96 rows x 64 k
            const int flat = tid + 256 * i;
            const int r = flat >> 4;
            const int k4 = flat & 15;
            float4 v = *(const float4*)(Wp + (size_t)r * D_INNER + kb + k4 * 4);
            wsh[k4*4+0][r] = v.x; wsh[k4*4+1][r] = v.y;
            wsh[k4*4+2][r] = v.z; wsh[k4*4+3][r] = v.w;
        }
        __syncthreads();

#pragma unroll 8
        for (int kk = 0; kk < PSC; ++kk) {
            float a[4], b[6];
#pragma unroll
            for (int i = 0; i < 4; ++i) a[i] = us[kk][ty * 4 + i];
#pragma unroll
            for (int j = 0; j < 6; ++j) b[j] = wsh[kk][tx + 16 * j];
#pragma unroll
            for (int i = 0; i < 4; ++i)
#pragma unroll
                for (int j = 0; j < 6; ++j) acc[i][j] += a[i] * b[j];
        }
    }

#pragma unroll
    for (int i = 0; i < 4; ++i)
#pragma unroll
        for (int j = 0; j < 6; ++j)
            atomicAdd(proj + (size_t)(bm + ty * 4 + i) * NPROJ + tx + 16 * j,
                      acc[i][j]);
}

// depthwise causal conv1d + bias + SiLU
__global__ __launch_bounds__(256) void conv_silu(
    const float* __restrict__ xz,
    const float* __restrict__ conv_w,
    const float* __restrict__ conv_b,
    float* __restrict__ u)
{
    const int idx = blockIdx.x * blockDim.x + threadIdx.x;
    const int d  = idx & (D_INNER - 1);
    const int bt = idx >> 11;
    const int t  = bt & (L_SEQ - 1);

    const float w0 = conv_w[d * 4 + 0];
    const float w1 = conv_w[d * 4 + 1];
    const float w2 = conv_w[d * 4 + 2];
    const float w3 = conv_w[d * 4 + 3];

    const float* col = xz + (size_t)bt * (2 * D_INNER) + d;
    float acc = conv_b[d];
    if (t >= 3) acc += col[-3 * 2 * D_INNER] * w0;
    if (t >= 2) acc += col[-2 * 2 * D_INNER] * w1;
    if (t >= 1) acc += col[-1 * 2 * D_INNER] * w2;
    acc += col[0] * w3;

    u[idx] = acc / (1.f + __expf(-acc));
}

// ---- chunked associative scan ---------------------------------------------
__global__ __launch_bounds__(256) void scan_phase_a(
    const float* __restrict__ xz,
    const float* __restrict__ u,
    const float* __restrict__ proj,
    const float* __restrict__ A_log,
    float* __restrict__ hloc,
    float* __restrict__ sumd)
{
    const int d = blockIdx.x * 256 + threadIdx.x;
    const int c = blockIdx.y;
    const int b = blockIdx.z;

    float a[D_STATE];
#pragma unroll
    for (int s = 0; s < D_STATE; ++s) a[s] = -__expf(A_log[d * D_STATE + s]);

    float h[D_STATE];
#pragma unroll
    for (int s = 0; s < D_STATE; ++s) h[s] = 0.f;
    float sd = 0.f;

    for (int t = c * CS; t < (c + 1) * CS; ++t) {
        const size_t bt = (size_t)b * L_SEQ + t;
        const float dv = xz[bt * (2 * D_INNER) + d];
        const float uv = u[bt * D_INNER + d];
        const float du = dv * uv;
        sd += dv;
        const float* pr = proj + bt * NPROJ;
#pragma unroll
        for (int s = 0; s < D_STATE; ++s)
            h[s] = __expf(dv * a[s]) * h[s] + du * pr[DT_RANK + s];
    }

    const size_t base = ((size_t)(b * NC + c) * D_STATE) * D_INNER + d;
#pragma unroll
    for (int s = 0; s < D_STATE; ++s) hloc[base + (size_t)s * D_INNER] = h[s];
    sumd[(size_t)(b * NC + c) * D_INNER + d] = sd;
}

__global__ __launch_bounds__(256) void scan_phase_b(
    const float* __restrict__ hloc,
    const float* __restrict__ sumd,
    const float* __restrict__ A_log,
    float* __restrict__ carry)
{
    const int d = blockIdx.x * 256 + threadIdx.x;
    const int b = blockIdx.y;

    float a[D_STATE];
#pragma unroll
    for (int s = 0; s < D_STATE; ++s) a[s] = -__expf(A_log[d * D_STATE + s]);

    float hc[D_STATE];
#pragma unroll
    for (int s = 0; s < D_STATE; ++s) {
        hc[s] = 0.f;
        carry[((size_t)(b * NC + 0) * D_STATE + s) * D_INNER + d] = 0.f;
    }

    for (int c = 1; c < NC; ++c) {
        const float sd = sumd[(size_t)(b * NC + c - 1) * D_INNER + d];
        const size_t pbase = ((size_t)(b * NC + c - 1) * D_STATE) * D_INNER + d;
        const size_t cbase = ((size_t)(b * NC + c) * D_STATE) * D_INNER + d;
#pragma unroll
        for (int s = 0; s < D_STATE; ++s) {
            const float P = __expf(a[s] * sd);
            hc[s] = P * hc[s] + hloc[pbase + (size_t)s * D_INNER];
            carry[cbase + (size_t)s * D_INNER] = hc[s];
        }
    }
}

__global__ __launch_bounds__(256) void scan_phase_c(
    const float* __restrict__ xz,
    float* uy,
    const float* __restrict__ proj,
    const float* __restrict__ A_log,
    const float* __restrict__ D_param,
    const float* __restrict__ carry)
{
    const int d = blockIdx.x * 256 + threadIdx.x;
    const int c = blockIdx.y;
    const int b = blockIdx.z;

    float a[D_STATE];
#pragma unroll
    for (int s = 0; s < D_STATE; ++s) a[s] = -__expf(A_log[d * D_STATE + s]);
    const float Dp = D_param[d];

    float h[D_STATE];
    const size_t cbase = ((size_t)(b * NC + c) * D_STATE) * D_INNER + d;
#pragma unroll
    for (int s = 0; s < D_STATE; ++s) h[s] = carry[cbase + (size_t)s * D_INNER];

    for (int t = c * CS; t < (c + 1) * CS; ++t) {
        const size_t bt = (size_t)b * L_SEQ + t;
        const float dv = xz[bt * (2 * D_INNER) + d];
        const float uv = uy[bt * D_INNER + d];
        const float du = dv * uv;
        const float* pr = proj + bt * NPROJ;

        float acc = 0.f;
#pragma unroll
        for (int s = 0; s < D_STATE; ++s) {
            h[s] = __expf(dv * a[s]) * h[s] + du * pr[DT_RANK + s];
            acc += h[s] * pr[DT_RANK + D_STATE + s];
        }
        const float yv = acc + Dp * uv;

        const float zv = xz[bt * (2 * D_INNER) + D_INNER + d];
        const float gate = zv / (1.f + __expf(-zv));
        uy[bt * D_INNER + d] = yv * gate;
    }
}

extern "C" void kernel_launch(void* const* d_in, const int* in_sizes, int n_in,
                              void* d_out, int out_size, void* d_ws, size_t ws_size,
                              hipStream_t stream)
{
    const float* x         = (const float*)d_in[0];
    const float* in_proj_w = (const float*)d_in[1];
    const float* conv_w    = (const float*)d_in[2];
    const float* conv_b    = (const float*)d_in[3];
    const float* x_proj_w  = (const float*)d_in[4];
    const float* dt_proj_w = (const float*)d_in[5];
    const float* dt_proj_b = (const float*)d_in[6];
    const float* A_log     = (const float*)d_in[7];
    const float* D_param   = (const float*)d_in[8];
    const float* out_proj_w= (const float*)d_in[9];
    float* out = (float*)d_out;

    float* xz    = (float*)d_ws;                    // [BL,4096] x_br->delta | z
    float* uy    = xz    + (size_t)BL * 4096;       // [BL,2048] u -> y
    float* proj  = uy    + (size_t)BL * 2048;       // [BL,96]
    float* hloc  = proj  + (size_t)BL * NPROJ;
    float* carry = hloc  + (size_t)B_SZ * NC * D_STATE * D_INNER;
    float* sumd  = carry + (size_t)B_SZ * NC * D_STATE * D_INNER;

    dim3 blk(256);

    // 1. xz = x @ in_proj_w^T   (2048 x 4096 x 1024)  [split-bf16 MFMA]
    gemm_mfma<128, 0><<<dim3((2 * D_INNER) / 128, BL / 128), blk, 0, stream>>>(
        x, D_MODEL, in_proj_w, D_MODEL, xz, 2 * D_INNER, D_MODEL, nullptr);

    // 2. u = silu(causal_dwconv(x_br) + conv_b)
    conv_silu<<<(BL * D_INNER) / 256, blk, 0, stream>>>(xz, conv_w, conv_b, uy);

    // 3. proj = u @ x_proj_w^T  (2048 x 96 x 2048)  [split-K + atomics]
    hipMemsetAsync(proj, 0, (size_t)BL * NPROJ * sizeof(float), stream);
    gemm_proj<<<dim3(8, BL / 64), blk, 0, stream>>>(uy, x_proj_w, proj);

    // 4. delta = softplus(proj[:,:64] @ dt_proj_w^T + dt_proj_b)  [MFMA + epi]
    //    written into xz cols 0..2047 (ldc = 4096)
    gemm_mfma<128, 1><<<dim3(D_INNER / 128, BL / 128), blk, 0, stream>>>(
        proj, NPROJ, dt_proj_w, DT_RANK, xz, 2 * D_INNER, DT_RANK, dt_proj_b);

    // 5. chunked SSM scan (3 phases) + D skip + silu(z) gate; y in-place over u
    scan_phase_a<<<dim3(D_INNER / 256, NC, B_SZ), blk, 0, stream>>>(
        xz, uy, proj, A_log, hloc, sumd);
    scan_phase_b<<<dim3(D_INNER / 256, B_SZ), blk, 0, stream>>>(
        hloc, sumd, A_log, carry);
    scan_phase_c<<<dim3(D_INNER / 256, NC, B_SZ), blk, 0, stream>>>(
        xz, uy, proj, A_log, D_param, carry);

    // 6. out = y @ out_proj_w^T (2048 x 1024 x 2048)  [MFMA, 128x64 tile]
    gemm_mfma<64, 0><<<dim3(D_MODEL / 64, BL / 128), blk, 0, stream>>>(
        uy, D_INNER, out_proj_w, D_INNER, out, D_MODEL, D_INNER, nullptr);
}

// Round 7
// 370.216 us; speedup vs baseline: 3.7322x; 1.0565x over previous
//
#include <hip/hip_runtime.h>
#include <hip/hip_bf16.h>

#define D_MODEL 1024
#define D_INNER 2048
#define D_STATE 16
#define D_CONV  4
#define DT_RANK 64
#define B_SZ    2
#define L_SEQ   1024
#define BL      (B_SZ * L_SEQ)          // 2048 rows
#define NPROJ   (DT_RANK + 2 * D_STATE) // 96
#define CS      64                      // scan chunk size
#define NC      (L_SEQ / CS)            // 16 chunks

typedef __attribute__((ext_vector_type(8))) short bf16x8;
typedef __attribute__((ext_vector_type(4))) float floatx4;
typedef unsigned short ushort_t;

__device__ __forceinline__ void mfma_bf16(floatx4& acc, bf16x8 a, bf16x8 b) {
    asm volatile("v_mfma_f32_16x16x32_bf16 %0, %1, %2, %0"
                 : "+v"(acc) : "v"(a), "v"(b));
}

__device__ __forceinline__ void cvt_hilo(float f, ushort_t& hi, ushort_t& lo) {
    __hip_bfloat16 h = __float2bfloat16(f);
    hi = *(ushort_t*)&h;
    __hip_bfloat16 l = __float2bfloat16(f - __bfloat162float(h));
    lo = *(ushort_t*)&l;
}

__device__ __forceinline__ void cvt_store4(float4 v, ushort_t* hi, ushort_t* lo) {
    ushort4 h, l;
    cvt_hilo(v.x, h.x, l.x);
    cvt_hilo(v.y, h.y, l.y);
    cvt_hilo(v.z, h.z, l.z);
    cvt_hilo(v.w, h.w, l.w);
    *(ushort4*)hi = h;
    *(ushort4*)lo = l;
}

// ---- fp32 -> bf16 hi/lo plane converters ----------------------------------
// Fused: in_proj_w (1048576 f4) | out_proj_w (524288) | dt_proj_w (32768) | x (524288)
#define N4_WI 1048576
#define N4_WO 524288
#define N4_WD 32768
#define N4_X  524288

__global__ __launch_bounds__(256) void cvt_static(
    const float* __restrict__ wi, ushort_t* wihi, ushort_t* wilo,
    const float* __restrict__ wo, ushort_t* wohi, ushort_t* wolo,
    const float* __restrict__ wd, ushort_t* wdhi, ushort_t* wdlo,
    const float* __restrict__ x,  ushort_t* xhi,  ushort_t* xlo)
{
    int i = blockIdx.x * 256 + threadIdx.x;
    const float* src; ushort_t *dh, *dl;
    if (i < N4_WI)                         { src = wi; dh = wihi; dl = wilo; }
    else if ((i -= N4_WI) < N4_WO)         { src = wo; dh = wohi; dl = wolo; }
    else if ((i -= N4_WO) < N4_WD)         { src = wd; dh = wdhi; dl = wdlo; }
    else { i -= N4_WD;                       src = x;  dh = xhi;  dl = xlo;  }
    float4 v = ((const float4*)src)[i];
    cvt_store4(v, dh + i * 4, dl + i * 4);
}

__global__ __launch_bounds__(256) void cvt_plain(
    const float* __restrict__ src, ushort_t* hi, ushort_t* lo)
{
    int i = blockIdx.x * 256 + threadIdx.x;
    float4 v = ((const float4*)src)[i];
    cvt_store4(v, hi + i * 4, lo + i * 4);
}

// proj[:, 0:64] (row stride 96) -> P planes [2048 x 64]
__global__ __launch_bounds__(256) void cvt_proj(
    const float* __restrict__ proj, ushort_t* hi, ushort_t* lo)
{
    int i = blockIdx.x * 256 + threadIdx.x;   // 32768 float4s
    const int r  = i >> 4;
    const int c4 = (i & 15) * 4;
    float4 v = *(const float4*)(proj + (size_t)r * NPROJ + c4);
    cvt_store4(v, hi + (size_t)r * 64 + c4, lo + (size_t)r * 64 + c4);
}

// ---------------- pre-split bf16 MFMA GEMM ---------------------------------
// C[M,N] = A[M,K] @ B[N,K]^T from hi/lo bf16 planes. 3-term split product.
// TM x TN tile, 256 threads = 4 waves (2x2), wave computes (TM/2)x(TN/2).
// EPI: 0 = none, 1 = softplus(acc + bias[col])
template <int TM, int TN, int EPI>
__global__ __launch_bounds__(256, 2) void gemm_pre(
    const ushort_t* __restrict__ Ahi, const ushort_t* __restrict__ Alo, int lda,
    const ushort_t* __restrict__ Bhi, const ushort_t* __restrict__ Blo, int ldb,
    float* __restrict__ C, int ldc, int K,
    const float* __restrict__ bias)
{
    constexpr int LDT = 40;   // padded LDS row stride (shorts): 80 B -> conflict-free
    constexpr int IT = TM / 32, JT = TN / 32;
    __shared__ __align__(16) ushort_t As[2][TM * LDT];
    __shared__ __align__(16) ushort_t Bs[2][TN * LDT];

    const int tid = threadIdx.x;
    const int bm = blockIdx.y * TM;
    const int bn = blockIdx.x * TN;

    const int wave = tid >> 6;
    const int lane = tid & 63;
    const int wm = (wave >> 1) * (TM / 2);
    const int wn = (wave & 1) * (TN / 2);
    const int ml = lane & 15;
    const int q  = lane >> 4;

    floatx4 acc[IT][JT];
#pragma unroll
    for (int i = 0; i < IT; ++i)
#pragma unroll
        for (int j = 0; j < JT; ++j) acc[i][j] = (floatx4)0.f;

    for (int k0 = 0; k0 < K; k0 += 32) {
        __syncthreads();
#pragma unroll
        for (int ci = 0; ci < TM / 64; ++ci) {   // A tile: TM x 32 shorts/plane
            const int flat = tid + 256 * ci;
            const int r = flat >> 2, kq = (flat & 3) * 8;
            *(uint4*)&As[0][r * LDT + kq] =
                *(const uint4*)(Ahi + (size_t)(bm + r) * lda + k0 + kq);
            *(uint4*)&As[1][r * LDT + kq] =
                *(const uint4*)(Alo + (size_t)(bm + r) * lda + k0 + kq);
        }
#pragma unroll
        for (int ci = 0; ci < TN / 64; ++ci) {   // B tile: TN x 32 shorts/plane
            const int flat = tid + 256 * ci;
            const int r = flat >> 2, kq = (flat & 3) * 8;
            *(uint4*)&Bs[0][r * LDT + kq] =
                *(const uint4*)(Bhi + (size_t)(bn + r) * ldb + k0 + kq);
            *(uint4*)&Bs[1][r * LDT + kq] =
                *(const uint4*)(Blo + (size_t)(bn + r) * ldb + k0 + kq);
        }
        __syncthreads();

        bf16x8 ah[IT], al[IT], bh[JT], bl[JT];
#pragma unroll
        for (int i = 0; i < IT; ++i) {
            const int r = wm + i * 16 + ml;
            ah[i] = *(const bf16x8*)&As[0][r * LDT + q * 8];
            al[i] = *(const bf16x8*)&As[1][r * LDT + q * 8];
        }
#pragma unroll
        for (int j = 0; j < JT; ++j) {
            const int r = wn + j * 16 + ml;
            bh[j] = *(const bf16x8*)&Bs[0][r * LDT + q * 8];
            bl[j] = *(const bf16x8*)&Bs[1][r * LDT + q * 8];
        }
#pragma unroll
        for (int i = 0; i < IT; ++i)
#pragma unroll
            for (int j = 0; j < JT; ++j) {
                mfma_bf16(acc[i][j], ah[i], bh[j]);
                mfma_bf16(acc[i][j], ah[i], bl[j]);
                mfma_bf16(acc[i][j], al[i], bh[j]);
            }
    }

    asm volatile("s_nop 7\n\ts_nop 7\n\ts_nop 7" ::: "memory");

#pragma unroll
    for (int i = 0; i < IT; ++i)
#pragma unroll
        for (int j = 0; j < JT; ++j)
#pragma unroll
            for (int r = 0; r < 4; ++r) {
                const int row = bm + wm + i * 16 + q * 4 + r;
                const int col = bn + wn + j * 16 + ml;
                float v = acc[i][j][r];
                if (EPI == 1) {
                    v += bias[col];
                    v = (v > 20.f) ? v : log1pf(__expf(v));
                }
                C[(size_t)row * ldc + col] = v;
            }
}

// ---------------- thin-N split-K GEMM for proj -----------------------------
#define PKC 256
#define PSC 64

__global__ __launch_bounds__(256) void gemm_proj(
    const float* __restrict__ u,
    const float* __restrict__ Wp,
    float* __restrict__ proj)   // pre-zeroed
{
    __shared__ float us[PSC][65];
    __shared__ float wsh[PSC][100];

    const int tid = threadIdx.x;
    const int bm = blockIdx.y * 64;
    const int kbase0 = blockIdx.x * PKC;

    const int tx = tid & 15;
    const int ty = tid >> 4;

    float acc[4][6];
#pragma unroll
    for (int i = 0; i < 4; ++i)
#pragma unroll
        for (int j = 0; j < 6; ++j) acc[i][j] = 0.f;

    for (int sc = 0; sc < PKC / PSC; ++sc) {
        const int kb = kbase0 + sc * PSC;
        __syncthreads();
#pragma unroll
        for (int i = 0; i < 4; ++i) {
            const int flat = tid + 256 * i;
            const int r = flat >> 4;
            const int k4 = flat & 15;
            float4 v = *(const float4*)(u + (size_t)(bm + r) * D_INNER + kb + k4 * 4);
            us[k4*4+0][r] = v.x; us[k4*4+1][r] = v.y;
            us[k4*4+2][r] = v.z; us[k4*4+3][r] = v.w;
        }
#pragma unroll
        for (int i = 0; i < 6; ++i) {
            const int flat = tid + 256 * i;
            const int r = flat >> 4;
            const int k4 = flat & 15;
            float4 v = *(const float4*)(Wp + (size_t)r * D_INNER + kb + k4 * 4);
            wsh[k4*4+0][r] = v.x; wsh[k4*4+1][r] = v.y;
            wsh[k4*4+2][r] = v.z; wsh[k4*4+3][r] = v.w;
        }
        __syncthreads();

#pragma unroll 8
        for (int kk = 0; kk < PSC; ++kk) {
            float a[4], b[6];
#pragma unroll
            for (int i = 0; i < 4; ++i) a[i] = us[kk][ty * 4 + i];
#pragma unroll
            for (int j = 0; j < 6; ++j) b[j] = wsh[kk][tx + 16 * j];
#pragma unroll
            for (int i = 0; i < 4; ++i)
#pragma unroll
                for (int j = 0; j < 6; ++j) acc[i][j] += a[i] * b[j];
        }
    }

#pragma unroll
    for (int i = 0; i < 4; ++i)
#pragma unroll
        for (int j = 0; j < 6; ++j)
            atomicAdd(proj + (size_t)(bm + ty * 4 + i) * NPROJ + tx + 16 * j,
                      acc[i][j]);
}

// depthwise causal conv1d + bias + SiLU
__global__ __launch_bounds__(256) void conv_silu(
    const float* __restrict__ xz,
    const float* __restrict__ conv_w,
    const float* __restrict__ conv_b,
    float* __restrict__ u)
{
    const int idx = blockIdx.x * blockDim.x + threadIdx.x;
    const int d  = idx & (D_INNER - 1);
    const int bt = idx >> 11;
    const int t  = bt & (L_SEQ - 1);

    const float w0 = conv_w[d * 4 + 0];
    const float w1 = conv_w[d * 4 + 1];
    const float w2 = conv_w[d * 4 + 2];
    const float w3 = conv_w[d * 4 + 3];

    const float* col = xz + (size_t)bt * (2 * D_INNER) + d;
    float acc = conv_b[d];
    if (t >= 3) acc += col[-3 * 2 * D_INNER] * w0;
    if (t >= 2) acc += col[-2 * 2 * D_INNER] * w1;
    if (t >= 1) acc += col[-1 * 2 * D_INNER] * w2;
    acc += col[0] * w3;

    u[idx] = acc / (1.f + __expf(-acc));
}

// ---- chunked associative scan ---------------------------------------------
__global__ __launch_bounds__(256) void scan_phase_a(
    const float* __restrict__ xz,
    const float* __restrict__ u,
    const float* __restrict__ proj,
    const float* __restrict__ A_log,
    float* __restrict__ hloc,
    float* __restrict__ sumd)
{
    const int d = blockIdx.x * 256 + threadIdx.x;
    const int c = blockIdx.y;
    const int b = blockIdx.z;

    float a[D_STATE];
#pragma unroll
    for (int s = 0; s < D_STATE; ++s) a[s] = -__expf(A_log[d * D_STATE + s]);

    float h[D_STATE];
#pragma unroll
    for (int s = 0; s < D_STATE; ++s) h[s] = 0.f;
    float sd = 0.f;

    for (int t = c * CS; t < (c + 1) * CS; ++t) {
        const size_t bt = (size_t)b * L_SEQ + t;
        const float dv = xz[bt * (2 * D_INNER) + d];
        const float uv = u[bt * D_INNER + d];
        const float du = dv * uv;
        sd += dv;
        const float* pr = proj + bt * NPROJ;
#pragma unroll
        for (int s = 0; s < D_STATE; ++s)
            h[s] = __expf(dv * a[s]) * h[s] + du * pr[DT_RANK + s];
    }

    const size_t base = ((size_t)(b * NC + c) * D_STATE) * D_INNER + d;
#pragma unroll
    for (int s = 0; s < D_STATE; ++s) hloc[base + (size_t)s * D_INNER] = h[s];
    sumd[(size_t)(b * NC + c) * D_INNER + d] = sd;
}

__global__ __launch_bounds__(256) void scan_phase_b(
    const float* __restrict__ hloc,
    const float* __restrict__ sumd,
    const float* __restrict__ A_log,
    float* __restrict__ carry)
{
    const int d = blockIdx.x * 256 + threadIdx.x;
    const int b = blockIdx.y;

    float a[D_STATE];
#pragma unroll
    for (int s = 0; s < D_STATE; ++s) a[s] = -__expf(A_log[d * D_STATE + s]);

    float hc[D_STATE];
#pragma unroll
    for (int s = 0; s < D_STATE; ++s) {
        hc[s] = 0.f;
        carry[((size_t)(b * NC + 0) * D_STATE + s) * D_INNER + d] = 0.f;
    }

    for (int c = 1; c < NC; ++c) {
        const float sd = sumd[(size_t)(b * NC + c - 1) * D_INNER + d];
        const size_t pbase = ((size_t)(b * NC + c - 1) * D_STATE) * D_INNER + d;
        const size_t cbase = ((size_t)(b * NC + c) * D_STATE) * D_INNER + d;
#pragma unroll
        for (int s = 0; s < D_STATE; ++s) {
            const float P = __expf(a[s] * sd);
            hc[s] = P * hc[s] + hloc[pbase + (size_t)s * D_INNER];
            carry[cbase + (size_t)s * D_INNER] = hc[s];
        }
    }
}

__global__ __launch_bounds__(256) void scan_phase_c(
    const float* __restrict__ xz,
    float* uy,
    const float* __restrict__ proj,
    const float* __restrict__ A_log,
    const float* __restrict__ D_param,
    const float* __restrict__ carry)
{
    const int d = blockIdx.x * 256 + threadIdx.x;
    const int c = blockIdx.y;
    const int b = blockIdx.z;

    float a[D_STATE];
#pragma unroll
    for (int s = 0; s < D_STATE; ++s) a[s] = -__expf(A_log[d * D_STATE + s]);
    const float Dp = D_param[d];

    float h[D_STATE];
    const size_t cbase = ((size_t)(b * NC + c) * D_STATE) * D_INNER + d;
#pragma unroll
    for (int s = 0; s < D_STATE; ++s) h[s] = carry[cbase + (size_t)s * D_INNER];

    for (int t = c * CS; t < (c + 1) * CS; ++t) {
        const size_t bt = (size_t)b * L_SEQ + t;
        const float dv = xz[bt * (2 * D_INNER) + d];
        const float uv = uy[bt * D_INNER + d];
        const float du = dv * uv;
        const float* pr = proj + bt * NPROJ;

        float acc = 0.f;
#pragma unroll
        for (int s = 0; s < D_STATE; ++s) {
            h[s] = __expf(dv * a[s]) * h[s] + du * pr[DT_RANK + s];
            acc += h[s] * pr[DT_RANK + D_STATE + s];
        }
        const float yv = acc + Dp * uv;

        const float zv = xz[bt * (2 * D_INNER) + D_INNER + d];
        const float gate = zv / (1.f + __expf(-zv));
        uy[bt * D_INNER + d] = yv * gate;
    }
}

extern "C" void kernel_launch(void* const* d_in, const int* in_sizes, int n_in,
                              void* d_out, int out_size, void* d_ws, size_t ws_size,
                              hipStream_t stream)
{
    const float* x         = (const float*)d_in[0];
    const float* in_proj_w = (const float*)d_in[1];
    const float* conv_w    = (const float*)d_in[2];
    const float* conv_b    = (const float*)d_in[3];
    const float* x_proj_w  = (const float*)d_in[4];
    const float* dt_proj_w = (const float*)d_in[5];
    const float* dt_proj_b = (const float*)d_in[6];
    const float* A_log     = (const float*)d_in[7];
    const float* D_param   = (const float*)d_in[8];
    const float* out_proj_w= (const float*)d_in[9];
    float* out = (float*)d_out;

    // Workspace (86 MB):
    float* xz    = (float*)d_ws;              // [BL,4096] f32: x_br -> delta | z
    float* u     = xz    + (size_t)BL * 4096; // [BL,2048] f32: u -> y
    float* proj  = u     + (size_t)BL * 2048; // [BL,96]   f32
    float* sumd  = proj  + (size_t)BL * NPROJ;
    float* hloc  = sumd  + (size_t)B_SZ * NC * D_INNER;             // 4 MB
    float* carry = hloc  + (size_t)B_SZ * NC * D_STATE * D_INNER;   // 4 MB
    ushort_t* Wihi = (ushort_t*)(carry + (size_t)B_SZ * NC * D_STATE * D_INNER);
    ushort_t* Wilo = Wihi + (size_t)4096 * 1024;
    ushort_t* Wohi = Wilo + (size_t)4096 * 1024;
    ushort_t* Wolo = Wohi + (size_t)1024 * 2048;
    ushort_t* Wdhi = Wolo + (size_t)1024 * 2048;
    ushort_t* Wdlo = Wdhi + (size_t)2048 * 64;
    ushort_t* Phi  = Wdlo + (size_t)2048 * 64;
    ushort_t* Plo  = Phi  + (size_t)2048 * 64;
    // Aliases (disjoint lifetimes):
    ushort_t* Xhi = (ushort_t*)hloc;   // X planes dead before scan_a writes hloc
    ushort_t* Xlo = (ushort_t*)carry;
    ushort_t* Yhi = (ushort_t*)xz;     // xz dead after scan_c
    ushort_t* Ylo = Yhi + (size_t)BL * D_INNER;

    dim3 blk(256);

    // 0. one-shot fp32 -> bf16 hi/lo conversion of weights + x
    cvt_static<<<(N4_WI + N4_WO + N4_WD + N4_X) / 256, blk, 0, stream>>>(
        in_proj_w, Wihi, Wilo, out_proj_w, Wohi, Wolo,
        dt_proj_w, Wdhi, Wdlo, x, Xhi, Xlo);

    // 1. xz = x @ in_proj_w^T   (2048 x 4096 x 1024)
    gemm_pre<128, 128, 0><<<dim3(4096 / 128, BL / 128), blk, 0, stream>>>(
        Xhi, Xlo, D_MODEL, Wihi, Wilo, D_MODEL, xz, 2 * D_INNER, D_MODEL, nullptr);

    // 2. u = silu(causal_dwconv(x_br) + conv_b)
    conv_silu<<<(BL * D_INNER) / 256, blk, 0, stream>>>(xz, conv_w, conv_b, u);

    // 3. proj = u @ x_proj_w^T  (2048 x 96 x 2048)  [split-K + atomics]
    hipMemsetAsync(proj, 0, (size_t)BL * NPROJ * sizeof(float), stream);
    gemm_proj<<<dim3(8, BL / 64), blk, 0, stream>>>(u, x_proj_w, proj);

    // 4. delta = softplus(proj[:,:64] @ dt_proj_w^T + b) -> xz cols 0..2047
    cvt_proj<<<(BL * 64 / 4) / 256, blk, 0, stream>>>(proj, Phi, Plo);
    gemm_pre<128, 128, 1><<<dim3(D_INNER / 128, BL / 128), blk, 0, stream>>>(
        Phi, Plo, DT_RANK, Wdhi, Wdlo, DT_RANK, xz, 2 * D_INNER, DT_RANK, dt_proj_b);

    // 5. chunked SSM scan + D skip + silu(z) gate; y in-place over u
    scan_phase_a<<<dim3(D_INNER / 256, NC, B_SZ), blk, 0, stream>>>(
        xz, u, proj, A_log, hloc, sumd);
    scan_phase_b<<<dim3(D_INNER / 256, B_SZ), blk, 0, stream>>>(
        hloc, sumd, A_log, carry);
    scan_phase_c<<<dim3(D_INNER / 256, NC, B_SZ), blk, 0, stream>>>(
        xz, u, proj, A_log, D_param, carry);

    // 6. out = y @ out_proj_w^T (2048 x 1024 x 2048), 64x64 tiles -> 512 blocks
    cvt_plain<<<((size_t)BL * D_INNER / 4) / 256, blk, 0, stream>>>(u, Yhi, Ylo);
    gemm_pre<64, 64, 0><<<dim3(D_MODEL / 64, BL / 64), blk, 0, stream>>>(
        Yhi, Ylo, D_INNER, Wohi, Wolo, D_INNER, out, D_MODEL, D_INNER, nullptr);
}

// Round 8
// 368.904 us; speedup vs baseline: 3.7454x; 1.0036x over previous
//
#include <hip/hip_runtime.h>
#include <hip/hip_bf16.h>

#define D_MODEL 1024
#define D_INNER 2048
#define D_STATE 16
#define D_CONV  4
#define DT_RANK 64
#define B_SZ    2
#define L_SEQ   1024
#define BL      (B_SZ * L_SEQ)          // 2048 rows
#define NPROJ   (DT_RANK + 2 * D_STATE) // 96
#define CS      64                      // scan chunk size
#define NC      (L_SEQ / CS)            // 16 chunks

typedef __attribute__((ext_vector_type(8))) short bf16x8;
typedef __attribute__((ext_vector_type(4))) float floatx4;
typedef unsigned short ushort_t;

__device__ __forceinline__ void mfma_bf16(floatx4& acc, bf16x8 a, bf16x8 b) {
    asm volatile("v_mfma_f32_16x16x32_bf16 %0, %1, %2, %0"
                 : "+v"(acc) : "v"(a), "v"(b));
}

__device__ __forceinline__ void cvt_hilo(float f, ushort_t& hi, ushort_t& lo) {
    __hip_bfloat16 h = __float2bfloat16(f);
    hi = *(ushort_t*)&h;
    __hip_bfloat16 l = __float2bfloat16(f - __bfloat162float(h));
    lo = *(ushort_t*)&l;
}

__device__ __forceinline__ void cvt_store4(float4 v, ushort_t* hi, ushort_t* lo) {
    ushort4 h, l;
    cvt_hilo(v.x, h.x, l.x);
    cvt_hilo(v.y, h.y, l.y);
    cvt_hilo(v.z, h.z, l.z);
    cvt_hilo(v.w, h.w, l.w);
    *(ushort4*)hi = h;
    *(ushort4*)lo = l;
}

// ---- fp32 -> bf16 hi/lo plane converter (weights + x, one launch) ---------
#define N4_WI 1048576
#define N4_WO 524288
#define N4_WD 32768
#define N4_X  524288

__global__ __launch_bounds__(256) void cvt_static(
    const float* __restrict__ wi, ushort_t* wihi, ushort_t* wilo,
    const float* __restrict__ wo, ushort_t* wohi, ushort_t* wolo,
    const float* __restrict__ wd, ushort_t* wdhi, ushort_t* wdlo,
    const float* __restrict__ x,  ushort_t* xhi,  ushort_t* xlo)
{
    int i = blockIdx.x * 256 + threadIdx.x;
    const float* src; ushort_t *dh, *dl;
    if (i < N4_WI)                         { src = wi; dh = wihi; dl = wilo; }
    else if ((i -= N4_WI) < N4_WO)         { src = wo; dh = wohi; dl = wolo; }
    else if ((i -= N4_WO) < N4_WD)         { src = wd; dh = wdhi; dl = wdlo; }
    else { i -= N4_WD;                       src = x;  dh = xhi;  dl = xlo;  }
    float4 v = ((const float4*)src)[i];
    cvt_store4(v, dh + i * 4, dl + i * 4);
}

// ---------------- pre-split bf16 MFMA GEMM ---------------------------------
// C[M,N] = A[M,K] @ B[N,K]^T from hi/lo bf16 planes (3-term split product).
// TM x TN tile, 256 threads = 4 waves (2x2), wave computes (TM/2)x(TN/2).
// EPI: 0 = none, 1 = softplus(acc + bias[col])
// CVTA: 1 = A is fp32 (Af/ldaf), converted to hi/lo during staging (TM=128 only)
template <int TM, int TN, int EPI, int CVTA>
__global__ __launch_bounds__(256, 2) void gemm_pre(
    const ushort_t* __restrict__ Ahi, const ushort_t* __restrict__ Alo, int lda,
    const float* __restrict__ Af, int ldaf,
    const ushort_t* __restrict__ Bhi, const ushort_t* __restrict__ Blo, int ldb,
    float* __restrict__ C, int ldc, int K,
    const float* __restrict__ bias)
{
    constexpr int LDT = 40;   // padded LDS row stride (shorts)
    constexpr int IT = TM / 32, JT = TN / 32;
    __shared__ __align__(16) ushort_t As[2][TM * LDT];
    __shared__ __align__(16) ushort_t Bs[2][TN * LDT];

    const int tid = threadIdx.x;
    const int bm = blockIdx.y * TM;
    const int bn = blockIdx.x * TN;

    const int wave = tid >> 6;
    const int lane = tid & 63;
    const int wm = (wave >> 1) * (TM / 2);
    const int wn = (wave & 1) * (TN / 2);
    const int ml = lane & 15;
    const int q  = lane >> 4;

    floatx4 acc[IT][JT];
#pragma unroll
    for (int i = 0; i < IT; ++i)
#pragma unroll
        for (int j = 0; j < JT; ++j) acc[i][j] = (floatx4)0.f;

    for (int k0 = 0; k0 < K; k0 += 32) {
        __syncthreads();
        if (CVTA) {
            // A fp32 -> hi/lo in-staging (128 rows x 32 k)
            const int r  = tid >> 1;
            const int kh = (tid & 1) * 16;
            ushort_t hi[16], lo[16];
#pragma unroll
            for (int c = 0; c < 4; ++c) {
                float4 v = *(const float4*)(Af + (size_t)(bm + r) * ldaf + k0 + kh + c * 4);
                cvt_store4(v, hi + c * 4, lo + c * 4);
            }
            *(uint4*)&As[0][r * LDT + kh + 0] = *(uint4*)(hi + 0);
            *(uint4*)&As[0][r * LDT + kh + 8] = *(uint4*)(hi + 8);
            *(uint4*)&As[1][r * LDT + kh + 0] = *(uint4*)(lo + 0);
            *(uint4*)&As[1][r * LDT + kh + 8] = *(uint4*)(lo + 8);
        } else {
#pragma unroll
            for (int ci = 0; ci < TM / 64; ++ci) {
                const int flat = tid + 256 * ci;
                const int r = flat >> 2, kq = (flat & 3) * 8;
                *(uint4*)&As[0][r * LDT + kq] =
                    *(const uint4*)(Ahi + (size_t)(bm + r) * lda + k0 + kq);
                *(uint4*)&As[1][r * LDT + kq] =
                    *(const uint4*)(Alo + (size_t)(bm + r) * lda + k0 + kq);
            }
        }
#pragma unroll
        for (int ci = 0; ci < TN / 64; ++ci) {
            const int flat = tid + 256 * ci;
            const int r = flat >> 2, kq = (flat & 3) * 8;
            *(uint4*)&Bs[0][r * LDT + kq] =
                *(const uint4*)(Bhi + (size_t)(bn + r) * ldb + k0 + kq);
            *(uint4*)&Bs[1][r * LDT + kq] =
                *(const uint4*)(Blo + (size_t)(bn + r) * ldb + k0 + kq);
        }
        __syncthreads();

        bf16x8 ah[IT], al[IT], bh[JT], bl[JT];
#pragma unroll
        for (int i = 0; i < IT; ++i) {
            const int r = wm + i * 16 + ml;
            ah[i] = *(const bf16x8*)&As[0][r * LDT + q * 8];
            al[i] = *(const bf16x8*)&As[1][r * LDT + q * 8];
        }
#pragma unroll
        for (int j = 0; j < JT; ++j) {
            const int r = wn + j * 16 + ml;
            bh[j] = *(const bf16x8*)&Bs[0][r * LDT + q * 8];
            bl[j] = *(const bf16x8*)&Bs[1][r * LDT + q * 8];
        }
#pragma unroll
        for (int i = 0; i < IT; ++i)
#pragma unroll
            for (int j = 0; j < JT; ++j) {
                mfma_bf16(acc[i][j], ah[i], bh[j]);
                mfma_bf16(acc[i][j], ah[i], bl[j]);
                mfma_bf16(acc[i][j], al[i], bh[j]);
            }
    }

    asm volatile("s_nop 7\n\ts_nop 7\n\ts_nop 7" ::: "memory");

#pragma unroll
    for (int i = 0; i < IT; ++i)
#pragma unroll
        for (int j = 0; j < JT; ++j)
#pragma unroll
            for (int r = 0; r < 4; ++r) {
                const int row = bm + wm + i * 16 + q * 4 + r;
                const int col = bn + wn + j * 16 + ml;
                float v = acc[i][j][r];
                if (EPI == 1) {
                    v += bias[col];
                    v = (v > 20.f) ? v : log1pf(__expf(v));
                }
                C[(size_t)row * ldc + col] = v;
            }
}

// ------- fused depthwise-conv+SiLU + thin-N split-K GEMM for proj ----------
// Computes u = silu(conv(x_br)+b) on the fly from xz, writes u once to global,
// and accumulates proj[BL,96] += u @ Wp^T via fp32 atomics (proj pre-zeroed).
#define PKC 256   // K per block
#define PSC 64    // K sub-chunk staged in LDS

__global__ __launch_bounds__(256) void gemm_proj_conv(
    const float* __restrict__ xz,      // [BL,4096], x_br = cols 0..2047
    const float* __restrict__ conv_w,  // [2048,4]
    const float* __restrict__ conv_b,  // [2048]
    const float* __restrict__ Wp,      // [96,2048]
    float* __restrict__ proj,          // pre-zeroed
    float* __restrict__ u_out)         // [BL,2048]
{
    __shared__ float us[PSC][65];
    __shared__ float wsh[PSC][100];

    const int tid = threadIdx.x;
    const int bm = blockIdx.y * 64;
    const int kbase0 = blockIdx.x * PKC;

    const int tx = tid & 15;
    const int ty = tid >> 4;

    float acc[4][6];
#pragma unroll
    for (int i = 0; i < 4; ++i)
#pragma unroll
        for (int j = 0; j < 6; ++j) acc[i][j] = 0.f;

    for (int sc = 0; sc < PKC / PSC; ++sc) {
        const int kb = kbase0 + sc * PSC;
        __syncthreads();
        // u tile: 64 rows x 64 k, computed from xz (conv + silu), stored + staged
#pragma unroll
        for (int i = 0; i < 4; ++i) {
            const int flat = tid + 256 * i;
            const int r  = flat >> 4;            // 0..63
            const int kk = (flat & 15) * 4;      // 0..60
            const int k  = kb + kk;
            const int rr = bm + r;
            const int t  = rr & (L_SEQ - 1);
            const float* base = xz + (size_t)rr * 4096 + k;
            float4 x0 = *(const float4*)(base);
            float4 x1 = (t >= 1) ? *(const float4*)(base - 4096)  : make_float4(0,0,0,0);
            float4 x2 = (t >= 2) ? *(const float4*)(base - 8192)  : make_float4(0,0,0,0);
            float4 x3 = (t >= 3) ? *(const float4*)(base - 12288) : make_float4(0,0,0,0);
            float4 cb = *(const float4*)(conv_b + k);
            float4 w0 = ((const float4*)conv_w)[k + 0];
            float4 w1 = ((const float4*)conv_w)[k + 1];
            float4 w2 = ((const float4*)conv_w)[k + 2];
            float4 w3 = ((const float4*)conv_w)[k + 3];
            float4 uo;
            {
                float a = cb.x + w0.x*x3.x + w0.y*x2.x + w0.z*x1.x + w0.w*x0.x;
                uo.x = a / (1.f + __expf(-a));
            }
            {
                float a = cb.y + w1.x*x3.y + w1.y*x2.y + w1.z*x1.y + w1.w*x0.y;
                uo.y = a / (1.f + __expf(-a));
            }
            {
                float a = cb.z + w2.x*x3.z + w2.y*x2.z + w2.z*x1.z + w2.w*x0.z;
                uo.z = a / (1.f + __expf(-a));
            }
            {
                float a = cb.w + w3.x*x3.w + w3.y*x2.w + w3.z*x1.w + w3.w*x0.w;
                uo.w = a / (1.f + __expf(-a));
            }
            us[kk + 0][r] = uo.x;
            us[kk + 1][r] = uo.y;
            us[kk + 2][r] = uo.z;
            us[kk + 3][r] = uo.w;
            *(float4*)(u_out + (size_t)rr * D_INNER + k) = uo;
        }
#pragma unroll
        for (int i = 0; i < 6; ++i) {            // w: 96 rows x 64 k
            const int flat = tid + 256 * i;
            const int r = flat >> 4;
            const int k4 = flat & 15;
            float4 v = *(const float4*)(Wp + (size_t)r * D_INNER + kb + k4 * 4);
            wsh[k4*4+0][r] = v.x; wsh[k4*4+1][r] = v.y;
            wsh[k4*4+2][r] = v.z; wsh[k4*4+3][r] = v.w;
        }
        __syncthreads();

#pragma unroll 8
        for (int kk = 0; kk < PSC; ++kk) {
            float a[4], b[6];
#pragma unroll
            for (int i = 0; i < 4; ++i) a[i] = us[kk][ty * 4 + i];
#pragma unroll
            for (int j = 0; j < 6; ++j) b[j] = wsh[kk][tx + 16 * j];
#pragma unroll
            for (int i = 0; i < 4; ++i)
#pragma unroll
                for (int j = 0; j < 6; ++j) acc[i][j] += a[i] * b[j];
        }
    }

#pragma unroll
    for (int i = 0; i < 4; ++i)
#pragma unroll
        for (int j = 0; j < 6; ++j)
            atomicAdd(proj + (size_t)(bm + ty * 4 + i) * NPROJ + tx + 16 * j,
                      acc[i][j]);
}

// ---- chunked associative scan ---------------------------------------------
__global__ __launch_bounds__(256) void scan_phase_a(
    const float* __restrict__ xz,
    const float* __restrict__ u,
    const float* __restrict__ proj,
    const float* __restrict__ A_log,
    float* __restrict__ hloc,
    float* __restrict__ sumd)
{
    const int d = blockIdx.x * 256 + threadIdx.x;
    const int c = blockIdx.y;
    const int b = blockIdx.z;

    float a[D_STATE];
#pragma unroll
    for (int s = 0; s < D_STATE; ++s) a[s] = -__expf(A_log[d * D_STATE + s]);

    float h[D_STATE];
#pragma unroll
    for (int s = 0; s < D_STATE; ++s) h[s] = 0.f;
    float sd = 0.f;

    for (int t = c * CS; t < (c + 1) * CS; ++t) {
        const size_t bt = (size_t)b * L_SEQ + t;
        const float dv = xz[bt * (2 * D_INNER) + d];
        const float uv = u[bt * D_INNER + d];
        const float du = dv * uv;
        sd += dv;
        const float* pr = proj + bt * NPROJ;
#pragma unroll
        for (int s = 0; s < D_STATE; ++s)
            h[s] = __expf(dv * a[s]) * h[s] + du * pr[DT_RANK + s];
    }

    const size_t base = ((size_t)(b * NC + c) * D_STATE) * D_INNER + d;
#pragma unroll
    for (int s = 0; s < D_STATE; ++s) hloc[base + (size_t)s * D_INNER] = h[s];
    sumd[(size_t)(b * NC + c) * D_INNER + d] = sd;
}

__global__ __launch_bounds__(256) void scan_phase_b(
    const float* __restrict__ hloc,
    const float* __restrict__ sumd,
    const float* __restrict__ A_log,
    float* __restrict__ carry)
{
    const int d = blockIdx.x * 256 + threadIdx.x;
    const int b = blockIdx.y;

    float a[D_STATE];
#pragma unroll
    for (int s = 0; s < D_STATE; ++s) a[s] = -__expf(A_log[d * D_STATE + s]);

    float hc[D_STATE];
#pragma unroll
    for (int s = 0; s < D_STATE; ++s) {
        hc[s] = 0.f;
        carry[((size_t)(b * NC + 0) * D_STATE + s) * D_INNER + d] = 0.f;
    }

    for (int c = 1; c < NC; ++c) {
        const float sd = sumd[(size_t)(b * NC + c - 1) * D_INNER + d];
        const size_t pbase = ((size_t)(b * NC + c - 1) * D_STATE) * D_INNER + d;
        const size_t cbase = ((size_t)(b * NC + c) * D_STATE) * D_INNER + d;
#pragma unroll
        for (int s = 0; s < D_STATE; ++s) {
            const float P = __expf(a[s] * sd);
            hc[s] = P * hc[s] + hloc[pbase + (size_t)s * D_INNER];
            carry[cbase + (size_t)s * D_INNER] = hc[s];
        }
    }
}

// Phase C: re-run chunk with carry-in; y + D skip + silu(z) gate,
// output written directly as bf16 hi/lo planes for the out-proj GEMM.
__global__ __launch_bounds__(256) void scan_phase_c(
    const float* __restrict__ xz,
    const float* __restrict__ u,
    const float* __restrict__ proj,
    const float* __restrict__ A_log,
    const float* __restrict__ D_param,
    const float* __restrict__ carry,
    ushort_t* __restrict__ Yhi,
    ushort_t* __restrict__ Ylo)
{
    const int d = blockIdx.x * 256 + threadIdx.x;
    const int c = blockIdx.y;
    const int b = blockIdx.z;

    float a[D_STATE];
#pragma unroll
    for (int s = 0; s < D_STATE; ++s) a[s] = -__expf(A_log[d * D_STATE + s]);
    const float Dp = D_param[d];

    float h[D_STATE];
    const size_t cbase = ((size_t)(b * NC + c) * D_STATE) * D_INNER + d;
#pragma unroll
    for (int s = 0; s < D_STATE; ++s) h[s] = carry[cbase + (size_t)s * D_INNER];

    for (int t = c * CS; t < (c + 1) * CS; ++t) {
        const size_t bt = (size_t)b * L_SEQ + t;
        const float dv = xz[bt * (2 * D_INNER) + d];
        const float uv = u[bt * D_INNER + d];
        const float du = dv * uv;
        const float* pr = proj + bt * NPROJ;

        float acc = 0.f;
#pragma unroll
        for (int s = 0; s < D_STATE; ++s) {
            h[s] = __expf(dv * a[s]) * h[s] + du * pr[DT_RANK + s];
            acc += h[s] * pr[DT_RANK + D_STATE + s];
        }
        const float yv = acc + Dp * uv;

        const float zv = xz[bt * (2 * D_INNER) + D_INNER + d];
        const float gate = zv / (1.f + __expf(-zv));
        ushort_t hh, ll;
        cvt_hilo(yv * gate, hh, ll);
        Yhi[bt * D_INNER + d] = hh;
        Ylo[bt * D_INNER + d] = ll;
    }
}

extern "C" void kernel_launch(void* const* d_in, const int* in_sizes, int n_in,
                              void* d_out, int out_size, void* d_ws, size_t ws_size,
                              hipStream_t stream)
{
    const float* x         = (const float*)d_in[0];
    const float* in_proj_w = (const float*)d_in[1];
    const float* conv_w    = (const float*)d_in[2];
    const float* conv_b    = (const float*)d_in[3];
    const float* x_proj_w  = (const float*)d_in[4];
    const float* dt_proj_w = (const float*)d_in[5];
    const float* dt_proj_b = (const float*)d_in[6];
    const float* A_log     = (const float*)d_in[7];
    const float* D_param   = (const float*)d_in[8];
    const float* out_proj_w= (const float*)d_in[9];
    float* out = (float*)d_out;

    // Workspace (~85 MB):
    float* xz    = (float*)d_ws;              // [BL,4096] f32: x_br -> delta | z
    float* u     = xz    + (size_t)BL * 4096; // [BL,2048] f32
    float* proj  = u     + (size_t)BL * 2048; // [BL,96]   f32
    float* sumd  = proj  + (size_t)BL * NPROJ;
    float* hloc  = sumd  + (size_t)B_SZ * NC * D_INNER;             // 4.2 MB
    float* carry = hloc  + (size_t)B_SZ * NC * D_STATE * D_INNER;   // 4.2 MB
    ushort_t* Wihi = (ushort_t*)(carry + (size_t)B_SZ * NC * D_STATE * D_INNER);
    ushort_t* Wilo = Wihi + (size_t)4096 * 1024;
    ushort_t* Wohi = Wilo + (size_t)4096 * 1024;
    ushort_t* Wolo = Wohi + (size_t)1024 * 2048;
    ushort_t* Wdhi = Wolo + (size_t)1024 * 2048;
    ushort_t* Wdlo = Wdhi + (size_t)2048 * 64;
    // Aliases (disjoint lifetimes):
    ushort_t* Xhi = (ushort_t*)hloc;   // X planes dead before scan_a writes hloc
    ushort_t* Xlo = (ushort_t*)carry;  // dead before scan_b writes carry
    ushort_t* Yhi = Wihi;              // Wi planes dead after GEMM1
    ushort_t* Ylo = Wilo;

    dim3 blk(256);

    // 0. one-shot fp32 -> bf16 hi/lo conversion of weights + x
    cvt_static<<<(N4_WI + N4_WO + N4_WD + N4_X) / 256, blk, 0, stream>>>(
        in_proj_w, Wihi, Wilo, out_proj_w, Wohi, Wolo,
        dt_proj_w, Wdhi, Wdlo, x, Xhi, Xlo);

    // 1. xz = x @ in_proj_w^T   (2048 x 4096 x 1024)
    gemm_pre<128, 128, 0, 0><<<dim3(4096 / 128, BL / 128), blk, 0, stream>>>(
        Xhi, Xlo, D_MODEL, nullptr, 0, Wihi, Wilo, D_MODEL,
        xz, 2 * D_INNER, D_MODEL, nullptr);

    // 2+3. fused conv+silu (u from xz) + proj = u @ x_proj_w^T [split-K atomics]
    hipMemsetAsync(proj, 0, (size_t)BL * NPROJ * sizeof(float), stream);
    gemm_proj_conv<<<dim3(8, BL / 64), blk, 0, stream>>>(
        xz, conv_w, conv_b, x_proj_w, proj, u);

    // 4. delta = softplus(proj[:,:64] @ dt_proj_w^T + b) -> xz cols 0..2047
    gemm_pre<128, 128, 1, 1><<<dim3(D_INNER / 128, BL / 128), blk, 0, stream>>>(
        nullptr, nullptr, 0, proj, NPROJ, Wdhi, Wdlo, DT_RANK,
        xz, 2 * D_INNER, DT_RANK, dt_proj_b);

    // 5. chunked SSM scan; phase C emits y as bf16 hi/lo planes
    scan_phase_a<<<dim3(D_INNER / 256, NC, B_SZ), blk, 0, stream>>>(
        xz, u, proj, A_log, hloc, sumd);
    scan_phase_b<<<dim3(D_INNER / 256, B_SZ), blk, 0, stream>>>(
        hloc, sumd, A_log, carry);
    scan_phase_c<<<dim3(D_INNER / 256, NC, B_SZ), blk, 0, stream>>>(
        xz, u, proj, A_log, D_param, carry, Yhi, Ylo);

    // 6. out = y @ out_proj_w^T (2048 x 1024 x 2048), 128x64 tiles -> 256 blocks
    gemm_pre<128, 64, 0, 0><<<dim3(D_MODEL / 64, BL / 128), blk, 0, stream>>>(
        Yhi, Ylo, D_INNER, nullptr, 0, Wohi, Wolo, D_INNER,
        out, D_MODEL, D_INNER, nullptr);
}

// Round 9
// 334.302 us; speedup vs baseline: 4.1331x; 1.1035x over previous
//
#include <hip/hip_runtime.h>
#include <hip/hip_bf16.h>

#define D_MODEL 1024
#define D_INNER 2048
#define D_STATE 16
#define D_CONV  4
#define DT_RANK 64
#define B_SZ    2
#define L_SEQ   1024
#define BL      (B_SZ * L_SEQ)          // 2048 rows
#define NPROJ   (DT_RANK + 2 * D_STATE) // 96
#define CS      32                      // scan chunk size
#define NC      (L_SEQ / CS)            // 32 chunks

typedef __attribute__((ext_vector_type(8))) short bf16x8;
typedef __attribute__((ext_vector_type(4))) float floatx4;
typedef unsigned short ushort_t;

__device__ __forceinline__ void mfma_bf16(floatx4& acc, bf16x8 a, bf16x8 b) {
    asm volatile("v_mfma_f32_16x16x32_bf16 %0, %1, %2, %0"
                 : "+v"(acc) : "v"(a), "v"(b));
}

__device__ __forceinline__ void cvt_hilo(float f, ushort_t& hi, ushort_t& lo) {
    __hip_bfloat16 h = __float2bfloat16(f);
    hi = *(ushort_t*)&h;
    __hip_bfloat16 l = __float2bfloat16(f - __bfloat162float(h));
    lo = *(ushort_t*)&l;
}

__device__ __forceinline__ void cvt_store4(float4 v, ushort_t* hi, ushort_t* lo) {
    ushort4 h, l;
    cvt_hilo(v.x, h.x, l.x);
    cvt_hilo(v.y, h.y, l.y);
    cvt_hilo(v.z, h.z, l.z);
    cvt_hilo(v.w, h.w, l.w);
    *(ushort4*)hi = h;
    *(ushort4*)lo = l;
}

// ---- fp32 -> bf16 hi/lo plane converter (weights + x, one launch) ---------
#define N4_WI 1048576
#define N4_WO 524288
#define N4_WD 32768
#define N4_X  524288

__global__ __launch_bounds__(256) void cvt_static(
    const float* __restrict__ wi, ushort_t* wihi, ushort_t* wilo,
    const float* __restrict__ wo, ushort_t* wohi, ushort_t* wolo,
    const float* __restrict__ wd, ushort_t* wdhi, ushort_t* wdlo,
    const float* __restrict__ x,  ushort_t* xhi,  ushort_t* xlo)
{
    int i = blockIdx.x * 256 + threadIdx.x;
    const float* src; ushort_t *dh, *dl;
    if (i < N4_WI)                         { src = wi; dh = wihi; dl = wilo; }
    else if ((i -= N4_WI) < N4_WO)         { src = wo; dh = wohi; dl = wolo; }
    else if ((i -= N4_WO) < N4_WD)         { src = wd; dh = wdhi; dl = wdlo; }
    else { i -= N4_WD;                       src = x;  dh = xhi;  dl = xlo;  }
    float4 v = ((const float4*)src)[i];
    cvt_store4(v, dh + i * 4, dl + i * 4);
}

// ---------------- pre-split bf16 MFMA GEMM ---------------------------------
// C[M,N] = A[M,K] @ B[N,K]^T from hi/lo bf16 planes (3-term split product).
// TM x TN tile, 256 threads = 4 waves (2x2), wave computes (TM/2)x(TN/2).
// EPI: 0 = none, 1 = softplus(acc + bias[col])  (KSPLIT==1 only)
// CVTA: 1 = A is fp32 (Af/ldaf), converted during staging (TM=128 only)
// KSPLIT: >1 = K-dim split across blockIdx.z, atomicAdd epilogue (C pre-zeroed)
template <int TM, int TN, int EPI, int CVTA, int KSPLIT>
__global__ __launch_bounds__(256, 2) void gemm_pre(
    const ushort_t* __restrict__ Ahi, const ushort_t* __restrict__ Alo, int lda,
    const float* __restrict__ Af, int ldaf,
    const ushort_t* __restrict__ Bhi, const ushort_t* __restrict__ Blo, int ldb,
    float* __restrict__ C, int ldc, int K,
    const float* __restrict__ bias)
{
    constexpr int LDT = 40;   // padded LDS row stride (shorts)
    constexpr int IT = TM / 32, JT = TN / 32;
    __shared__ __align__(16) ushort_t As[2][TM * LDT];
    __shared__ __align__(16) ushort_t Bs[2][TN * LDT];

    const int tid = threadIdx.x;
    const int bm = blockIdx.y * TM;
    const int bn = blockIdx.x * TN;
    const int kstart = (KSPLIT > 1) ? blockIdx.z * (K / KSPLIT) : 0;
    const int kend   = (KSPLIT > 1) ? kstart + K / KSPLIT : K;

    const int wave = tid >> 6;
    const int lane = tid & 63;
    const int wm = (wave >> 1) * (TM / 2);
    const int wn = (wave & 1) * (TN / 2);
    const int ml = lane & 15;
    const int q  = lane >> 4;

    floatx4 acc[IT][JT];
#pragma unroll
    for (int i = 0; i < IT; ++i)
#pragma unroll
        for (int j = 0; j < JT; ++j) acc[i][j] = (floatx4)0.f;

    for (int k0 = kstart; k0 < kend; k0 += 32) {
        __syncthreads();
        if (CVTA) {
            // A fp32 -> hi/lo in-staging (128 rows x 32 k)
            const int r  = tid >> 1;
            const int kh = (tid & 1) * 16;
            ushort_t hi[16], lo[16];
#pragma unroll
            for (int c = 0; c < 4; ++c) {
                float4 v = *(const float4*)(Af + (size_t)(bm + r) * ldaf + k0 + kh + c * 4);
                cvt_store4(v, hi + c * 4, lo + c * 4);
            }
            *(uint4*)&As[0][r * LDT + kh + 0] = *(uint4*)(hi + 0);
            *(uint4*)&As[0][r * LDT + kh + 8] = *(uint4*)(hi + 8);
            *(uint4*)&As[1][r * LDT + kh + 0] = *(uint4*)(lo + 0);
            *(uint4*)&As[1][r * LDT + kh + 8] = *(uint4*)(lo + 8);
        } else {
#pragma unroll
            for (int ci = 0; ci < TM / 64; ++ci) {
                const int flat = tid + 256 * ci;
                const int r = flat >> 2, kq = (flat & 3) * 8;
                *(uint4*)&As[0][r * LDT + kq] =
                    *(const uint4*)(Ahi + (size_t)(bm + r) * lda + k0 + kq);
                *(uint4*)&As[1][r * LDT + kq] =
                    *(const uint4*)(Alo + (size_t)(bm + r) * lda + k0 + kq);
            }
        }
#pragma unroll
        for (int ci = 0; ci < TN / 64; ++ci) {
            const int flat = tid + 256 * ci;
            const int r = flat >> 2, kq = (flat & 3) * 8;
            *(uint4*)&Bs[0][r * LDT + kq] =
                *(const uint4*)(Bhi + (size_t)(bn + r) * ldb + k0 + kq);
            *(uint4*)&Bs[1][r * LDT + kq] =
                *(const uint4*)(Blo + (size_t)(bn + r) * ldb + k0 + kq);
        }
        __syncthreads();

        bf16x8 ah[IT], al[IT], bh[JT], bl[JT];
#pragma unroll
        for (int i = 0; i < IT; ++i) {
            const int r = wm + i * 16 + ml;
            ah[i] = *(const bf16x8*)&As[0][r * LDT + q * 8];
            al[i] = *(const bf16x8*)&As[1][r * LDT + q * 8];
        }
#pragma unroll
        for (int j = 0; j < JT; ++j) {
            const int r = wn + j * 16 + ml;
            bh[j] = *(const bf16x8*)&Bs[0][r * LDT + q * 8];
            bl[j] = *(const bf16x8*)&Bs[1][r * LDT + q * 8];
        }
#pragma unroll
        for (int i = 0; i < IT; ++i)
#pragma unroll
            for (int j = 0; j < JT; ++j) {
                mfma_bf16(acc[i][j], ah[i], bh[j]);
                mfma_bf16(acc[i][j], ah[i], bl[j]);
                mfma_bf16(acc[i][j], al[i], bh[j]);
            }
    }

    asm volatile("s_nop 7\n\ts_nop 7\n\ts_nop 7" ::: "memory");

#pragma unroll
    for (int i = 0; i < IT; ++i)
#pragma unroll
        for (int j = 0; j < JT; ++j)
#pragma unroll
            for (int r = 0; r < 4; ++r) {
                const int row = bm + wm + i * 16 + q * 4 + r;
                const int col = bn + wn + j * 16 + ml;
                float v = acc[i][j][r];
                if (KSPLIT > 1) {
                    atomicAdd(C + (size_t)row * ldc + col, v);
                } else {
                    if (EPI == 1) {
                        v += bias[col];
                        v = (v > 20.f) ? v : log1pf(__expf(v));
                    }
                    C[(size_t)row * ldc + col] = v;
                }
            }
}

// ------- fused depthwise-conv+SiLU + thin-N split-K GEMM for proj ----------
#define PKC 128   // K per block (16 k-splits -> 512 blocks)
#define PSC 64    // K sub-chunk staged in LDS

__global__ __launch_bounds__(256) void gemm_proj_conv(
    const float* __restrict__ xz,      // [BL,4096], x_br = cols 0..2047
    const float* __restrict__ conv_w,  // [2048,4]
    const float* __restrict__ conv_b,  // [2048]
    const float* __restrict__ Wp,      // [96,2048]
    float* __restrict__ proj,          // pre-zeroed
    float* __restrict__ u_out)         // [BL,2048]
{
    __shared__ float us[PSC][65];
    __shared__ float wsh[PSC][100];

    const int tid = threadIdx.x;
    const int bm = blockIdx.y * 64;
    const int kbase0 = blockIdx.x * PKC;

    const int tx = tid & 15;
    const int ty = tid >> 4;

    float acc[4][6];
#pragma unroll
    for (int i = 0; i < 4; ++i)
#pragma unroll
        for (int j = 0; j < 6; ++j) acc[i][j] = 0.f;

    for (int sc = 0; sc < PKC / PSC; ++sc) {
        const int kb = kbase0 + sc * PSC;
        __syncthreads();
#pragma unroll
        for (int i = 0; i < 4; ++i) {
            const int flat = tid + 256 * i;
            const int r  = flat >> 4;
            const int kk = (flat & 15) * 4;
            const int k  = kb + kk;
            const int rr = bm + r;
            const int t  = rr & (L_SEQ - 1);
            const float* base = xz + (size_t)rr * 4096 + k;
            float4 x0 = *(const float4*)(base);
            float4 x1 = (t >= 1) ? *(const float4*)(base - 4096)  : make_float4(0,0,0,0);
            float4 x2 = (t >= 2) ? *(const float4*)(base - 8192)  : make_float4(0,0,0,0);
            float4 x3 = (t >= 3) ? *(const float4*)(base - 12288) : make_float4(0,0,0,0);
            float4 cb = *(const float4*)(conv_b + k);
            float4 w0 = ((const float4*)conv_w)[k + 0];
            float4 w1 = ((const float4*)conv_w)[k + 1];
            float4 w2 = ((const float4*)conv_w)[k + 2];
            float4 w3 = ((const float4*)conv_w)[k + 3];
            float4 uo;
            { float a = cb.x + w0.x*x3.x + w0.y*x2.x + w0.z*x1.x + w0.w*x0.x;
              uo.x = a / (1.f + __expf(-a)); }
            { float a = cb.y + w1.x*x3.y + w1.y*x2.y + w1.z*x1.y + w1.w*x0.y;
              uo.y = a / (1.f + __expf(-a)); }
            { float a = cb.z + w2.x*x3.z + w2.y*x2.z + w2.z*x1.z + w2.w*x0.z;
              uo.z = a / (1.f + __expf(-a)); }
            { float a = cb.w + w3.x*x3.w + w3.y*x2.w + w3.z*x1.w + w3.w*x0.w;
              uo.w = a / (1.f + __expf(-a)); }
            us[kk + 0][r] = uo.x;
            us[kk + 1][r] = uo.y;
            us[kk + 2][r] = uo.z;
            us[kk + 3][r] = uo.w;
            *(float4*)(u_out + (size_t)rr * D_INNER + k) = uo;
        }
#pragma unroll
        for (int i = 0; i < 6; ++i) {
            const int flat = tid + 256 * i;
            const int r = flat >> 4;
            const int k4 = flat & 15;
            float4 v = *(const float4*)(Wp + (size_t)r * D_INNER + kb + k4 * 4);
            wsh[k4*4+0][r] = v.x; wsh[k4*4+1][r] = v.y;
            wsh[k4*4+2][r] = v.z; wsh[k4*4+3][r] = v.w;
        }
        __syncthreads();

#pragma unroll 8
        for (int kk = 0; kk < PSC; ++kk) {
            float a[4], b[6];
#pragma unroll
            for (int i = 0; i < 4; ++i) a[i] = us[kk][ty * 4 + i];
#pragma unroll
            for (int j = 0; j < 6; ++j) b[j] = wsh[kk][tx + 16 * j];
#pragma unroll
            for (int i = 0; i < 4; ++i)
#pragma unroll
                for (int j = 0; j < 6; ++j) acc[i][j] += a[i] * b[j];
        }
    }

#pragma unroll
    for (int i = 0; i < 4; ++i)
#pragma unroll
        for (int j = 0; j < 6; ++j)
            atomicAdd(proj + (size_t)(bm + ty * 4 + i) * NPROJ + tx + 16 * j,
                      acc[i][j]);
}

// ---- chunked associative scan (NC=32 chunks of CS=32) ---------------------
__global__ __launch_bounds__(256) void scan_phase_a(
    const float* __restrict__ xz,
    const float* __restrict__ u,
    const float* __restrict__ proj,
    const float* __restrict__ A_log,
    float* __restrict__ hloc,
    float* __restrict__ sumd)
{
    const int d = blockIdx.x * 256 + threadIdx.x;
    const int c = blockIdx.y;
    const int b = blockIdx.z;

    float a[D_STATE];
#pragma unroll
    for (int s = 0; s < D_STATE; ++s) a[s] = -__expf(A_log[d * D_STATE + s]);

    float h[D_STATE];
#pragma unroll
    for (int s = 0; s < D_STATE; ++s) h[s] = 0.f;
    float sd = 0.f;

    for (int t = c * CS; t < (c + 1) * CS; ++t) {
        const size_t bt = (size_t)b * L_SEQ + t;
        const float dv = xz[bt * (2 * D_INNER) + d];
        const float uv = u[bt * D_INNER + d];
        const float du = dv * uv;
        sd += dv;
        const float* pr = proj + bt * NPROJ;
#pragma unroll
        for (int s = 0; s < D_STATE; ++s)
            h[s] = __expf(dv * a[s]) * h[s] + du * pr[DT_RANK + s];
    }

    const size_t base = ((size_t)(b * NC + c) * D_STATE) * D_INNER + d;
#pragma unroll
    for (int s = 0; s < D_STATE; ++s) hloc[base + (size_t)s * D_INNER] = h[s];
    sumd[(size_t)(b * NC + c) * D_INNER + d] = sd;
}

__global__ __launch_bounds__(256) void scan_phase_b(
    const float* __restrict__ hloc,
    const float* __restrict__ sumd,
    const float* __restrict__ A_log,
    float* __restrict__ carry)
{
    const int d = blockIdx.x * 256 + threadIdx.x;
    const int b = blockIdx.y;

    float a[D_STATE];
#pragma unroll
    for (int s = 0; s < D_STATE; ++s) a[s] = -__expf(A_log[d * D_STATE + s]);

    float hc[D_STATE];
#pragma unroll
    for (int s = 0; s < D_STATE; ++s) {
        hc[s] = 0.f;
        carry[((size_t)(b * NC + 0) * D_STATE + s) * D_INNER + d] = 0.f;
    }

    for (int c = 1; c < NC; ++c) {
        const float sd = sumd[(size_t)(b * NC + c - 1) * D_INNER + d];
        const size_t pbase = ((size_t)(b * NC + c - 1) * D_STATE) * D_INNER + d;
        const size_t cbase = ((size_t)(b * NC + c) * D_STATE) * D_INNER + d;
#pragma unroll
        for (int s = 0; s < D_STATE; ++s) {
            const float P = __expf(a[s] * sd);
            hc[s] = P * hc[s] + hloc[pbase + (size_t)s * D_INNER];
            carry[cbase + (size_t)s * D_INNER] = hc[s];
        }
    }
}

// Phase C: re-run chunk with carry-in; y + D skip + silu(z) gate,
// output written directly as bf16 hi/lo planes for the out-proj GEMM.
__global__ __launch_bounds__(256) void scan_phase_c(
    const float* __restrict__ xz,
    const float* __restrict__ u,
    const float* __restrict__ proj,
    const float* __restrict__ A_log,
    const float* __restrict__ D_param,
    const float* __restrict__ carry,
    ushort_t* __restrict__ Yhi,
    ushort_t* __restrict__ Ylo)
{
    const int d = blockIdx.x * 256 + threadIdx.x;
    const int c = blockIdx.y;
    const int b = blockIdx.z;

    float a[D_STATE];
#pragma unroll
    for (int s = 0; s < D_STATE; ++s) a[s] = -__expf(A_log[d * D_STATE + s]);
    const float Dp = D_param[d];

    float h[D_STATE];
    const size_t cbase = ((size_t)(b * NC + c) * D_STATE) * D_INNER + d;
#pragma unroll
    for (int s = 0; s < D_STATE; ++s) h[s] = carry[cbase + (size_t)s * D_INNER];

    for (int t = c * CS; t < (c + 1) * CS; ++t) {
        const size_t bt = (size_t)b * L_SEQ + t;
        const float dv = xz[bt * (2 * D_INNER) + d];
        const float uv = u[bt * D_INNER + d];
        const float du = dv * uv;
        const float* pr = proj + bt * NPROJ;

        float acc = 0.f;
#pragma unroll
        for (int s = 0; s < D_STATE; ++s) {
            h[s] = __expf(dv * a[s]) * h[s] + du * pr[DT_RANK + s];
            acc += h[s] * pr[DT_RANK + D_STATE + s];
        }
        const float yv = acc + Dp * uv;

        const float zv = xz[bt * (2 * D_INNER) + D_INNER + d];
        const float gate = zv / (1.f + __expf(-zv));
        ushort_t hh, ll;
        cvt_hilo(yv * gate, hh, ll);
        Yhi[bt * D_INNER + d] = hh;
        Ylo[bt * D_INNER + d] = ll;
    }
}

extern "C" void kernel_launch(void* const* d_in, const int* in_sizes, int n_in,
                              void* d_out, int out_size, void* d_ws, size_t ws_size,
                              hipStream_t stream)
{
    const float* x         = (const float*)d_in[0];
    const float* in_proj_w = (const float*)d_in[1];
    const float* conv_w    = (const float*)d_in[2];
    const float* conv_b    = (const float*)d_in[3];
    const float* x_proj_w  = (const float*)d_in[4];
    const float* dt_proj_w = (const float*)d_in[5];
    const float* dt_proj_b = (const float*)d_in[6];
    const float* A_log     = (const float*)d_in[7];
    const float* D_param   = (const float*)d_in[8];
    const float* out_proj_w= (const float*)d_in[9];
    float* out = (float*)d_out;

    // Workspace layout (~85.7 MB), with lifetime-based aliases:
    float* xz    = (float*)d_ws;              // [BL,4096] f32: x_br -> delta | z
    float* u     = xz    + (size_t)BL * 4096; // [BL,2048] f32
    float* proj  = u     + (size_t)BL * 2048; // [BL,96]   f32
    float* sumd  = proj  + (size_t)BL * NPROJ;                     // 0.52 MB
    float* carry = sumd  + (size_t)B_SZ * NC * D_INNER;            // 8.39 MB
    ushort_t* Wihi = (ushort_t*)(carry + (size_t)B_SZ * NC * D_STATE * D_INNER);
    ushort_t* Wilo = Wihi + (size_t)4096 * 1024;   // 8.39 MB each
    ushort_t* Wohi = Wilo + (size_t)4096 * 1024;
    ushort_t* Wolo = Wohi + (size_t)1024 * 2048;
    ushort_t* Wdhi = Wolo + (size_t)1024 * 2048;
    ushort_t* Wdlo = Wdhi + (size_t)2048 * 64;
    // Aliases (disjoint lifetimes):
    ushort_t* Xhi  = (ushort_t*)carry;  // X planes dead before scan_b writes carry
    ushort_t* Xlo  = Xhi + (size_t)BL * D_MODEL;
    float*    hloc = (float*)Wihi;      // Wi planes dead after GEMM1; hloc dead after scan_b
    ushort_t* Yhi  = Wihi;              // written by scan_c (after hloc is dead)
    ushort_t* Ylo  = Wilo;

    dim3 blk(256);

    // 0. one-shot fp32 -> bf16 hi/lo conversion of weights + x
    cvt_static<<<(N4_WI + N4_WO + N4_WD + N4_X) / 256, blk, 0, stream>>>(
        in_proj_w, Wihi, Wilo, out_proj_w, Wohi, Wolo,
        dt_proj_w, Wdhi, Wdlo, x, Xhi, Xlo);

    // 1. xz = x @ in_proj_w^T   (2048 x 4096 x 1024)
    gemm_pre<128, 128, 0, 0, 1><<<dim3(4096 / 128, BL / 128), blk, 0, stream>>>(
        Xhi, Xlo, D_MODEL, nullptr, 0, Wihi, Wilo, D_MODEL,
        xz, 2 * D_INNER, D_MODEL, nullptr);

    // 2+3. fused conv+silu (u from xz) + proj = u @ x_proj_w^T [split-K atomics]
    hipMemsetAsync(proj, 0, (size_t)BL * NPROJ * sizeof(float), stream);
    gemm_proj_conv<<<dim3(D_INNER / PKC, BL / 64), blk, 0, stream>>>(
        xz, conv_w, conv_b, x_proj_w, proj, u);

    // 4. delta = softplus(proj[:,:64] @ dt_proj_w^T + b) -> xz cols 0..2047
    gemm_pre<128, 128, 1, 1, 1><<<dim3(D_INNER / 128, BL / 128), blk, 0, stream>>>(
        nullptr, nullptr, 0, proj, NPROJ, Wdhi, Wdlo, DT_RANK,
        xz, 2 * D_INNER, DT_RANK, dt_proj_b);

    // 5. chunked SSM scan (NC=32); phase C emits y as bf16 hi/lo planes
    scan_phase_a<<<dim3(D_INNER / 256, NC, B_SZ), blk, 0, stream>>>(
        xz, u, proj, A_log, hloc, sumd);
    scan_phase_b<<<dim3(D_INNER / 256, B_SZ), blk, 0, stream>>>(
        hloc, sumd, A_log, carry);
    scan_phase_c<<<dim3(D_INNER / 256, NC, B_SZ), blk, 0, stream>>>(
        xz, u, proj, A_log, D_param, carry, Yhi, Ylo);

    // 6. out = y @ out_proj_w^T (2048 x 1024 x 2048), split-K=2 -> 512 blocks
    hipMemsetAsync(out, 0, (size_t)BL * D_MODEL * sizeof(float), stream);
    gemm_pre<128, 64, 0, 0, 2><<<dim3(D_MODEL / 64, BL / 128, 2), blk, 0, stream>>>(
        Yhi, Ylo, D_INNER, nullptr, 0, Wohi, Wolo, D_INNER,
        out, D_MODEL, D_INNER, nullptr);
}